// Round 2
// baseline (6722.616 us; speedup 1.0000x reference)
//
#include <hip/hip_runtime.h>
#include <math.h>

#define LB __launch_bounds__(256)

constexpr int BATCH = 32, NFEAT = 1024, FDIM = 768, NSLOT = 24;
constexpr int NH = 4, DH = 64, NITER = 3;
constexpr int MF = BATCH * NFEAT;   // 32768 feature rows
constexpr int MS = BATCH * NSLOT;   // 768 slot rows
constexpr float QSCALE = 0.125f;    // dh^-0.5
constexpr float ATTN_EPS = 1e-8f;
constexpr float LNEPS = 1e-5f;

// ---- prep: Wg = W * gamma (over k), cconst[c] = sum_k beta[k]*W[c][k] ----
// rows 0..255 -> Wk, 256..511 -> Wv, 512..767 -> Wq
__global__ LB void k_prep(const float* __restrict__ Wk, const float* __restrict__ Wv,
                          const float* __restrict__ Wq,
                          const float* __restrict__ g_in, const float* __restrict__ b_in,
                          const float* __restrict__ g_s, const float* __restrict__ b_s,
                          float* __restrict__ Wgk, float* __restrict__ Wgv,
                          float* __restrict__ Wgq, float* __restrict__ cconst) {
  const int r = blockIdx.x;
  const int t = threadIdx.x;
  const float* src; float* dst; const float* g; const float* bb; int len;
  if (r < 256)      { src = Wk + (size_t)r * FDIM;         dst = Wgk + (size_t)r * FDIM;         g = g_in; bb = b_in; len = FDIM; }
  else if (r < 512) { src = Wv + (size_t)(r - 256) * FDIM; dst = Wgv + (size_t)(r - 256) * FDIM; g = g_in; bb = b_in; len = FDIM; }
  else              { src = Wq + (size_t)(r - 512) * 256;  dst = Wgq + (size_t)(r - 512) * 256;  g = g_s;  bb = b_s;  len = 256; }
  float s = 0.f;
  for (int k = t; k < len; k += 256) { float w = src[k]; dst[k] = w * g[k]; s += bb[k] * w; }
  __shared__ float red[256];
  red[t] = s; __syncthreads();
  for (int o = 128; o > 0; o >>= 1) { if (t < o) red[t] += red[t + o]; __syncthreads(); }
  if (t == 0) cconst[r] = red[0];
}

// ---------------- per-row mean/rstd of features ----------------
// block = 4 rows x 64 lanes, float4 loads, shuffle reduce
__global__ LB void k_rowstats(const float* __restrict__ x, float* __restrict__ stats) {
  const int row = blockIdx.x * 4 + (threadIdx.x >> 6);
  const int lane = threadIdx.x & 63;
  const float* xr = x + (size_t)row * FDIM;
  float s = 0.f, sq = 0.f;
#pragma unroll
  for (int i = 0; i < 3; ++i) {
    float4 v = *(const float4*)(xr + i * 256 + lane * 4);
    s += v.x + v.y + v.z + v.w;
    sq += v.x * v.x + v.y * v.y + v.z * v.z + v.w * v.w;
  }
#pragma unroll
  for (int o = 32; o > 0; o >>= 1) { s += __shfl_down(s, o, 64); sq += __shfl_down(sq, o, 64); }
  if (lane == 0) {
    float m = s / (float)FDIM;
    float var = sq / (float)FDIM - m * m;
    stats[row * 2] = m;
    stats[row * 2 + 1] = 1.f / sqrtf(var + LNEPS);
  }
}

// -------- fused LN(features) @ Wg^T -> k,v. 128x128 tiles, BK=16, dbuf LDS --------
// conflict-free reads: per-thread cols = two float4 strips at tn0 and 64+tn0
__global__ __launch_bounds__(256, 4) void k_lnkv(
    const float* __restrict__ x, const float* __restrict__ stats,
    const float* __restrict__ Wgk, const float* __restrict__ Wgv,
    const float* __restrict__ cconst,
    float* __restrict__ kout, float* __restrict__ vout) {
  __shared__ float As[2][16][128];
  __shared__ float Bs[2][16][128];
  const int row0 = blockIdx.x * 128;
  const int col0 = blockIdx.y * 128;       // 0,128 -> k ; 256,384 -> v
  const float* W = (col0 < 256) ? Wgk : Wgv;
  float* Cout = (col0 < 256) ? kout : vout;
  const int coff = (col0 < 256) ? 0 : 256;
  const int wc0 = col0 & 255;
  const int t = threadIdx.x;
  const int lm = t >> 1;                    // staging row 0..127
  const int lk = (t & 1) * 8;               // 0 or 8
  const int tm0 = (t >> 4) * 8;             // 8 output rows
  const int tn0 = (t & 15) * 4;             // col strip base (strips at +0, +64)
  const float mrow = stats[(row0 + lm) * 2];
  const float rrow = stats[(row0 + lm) * 2 + 1];
  const float* arow = x + (size_t)(row0 + lm) * FDIM;
  const float* wrow = W + (size_t)(wc0 + lm) * FDIM;
  float acc[8][8] = {};
  float4 av0, av1, wv0, wv1;

  // prologue: fetch + stage step 0
  av0 = *(const float4*)(arow + lk);
  av1 = *(const float4*)(arow + lk + 4);
  wv0 = *(const float4*)(wrow + lk);
  wv1 = *(const float4*)(wrow + lk + 4);
  As[0][lk + 0][lm] = (av0.x - mrow) * rrow;
  As[0][lk + 1][lm] = (av0.y - mrow) * rrow;
  As[0][lk + 2][lm] = (av0.z - mrow) * rrow;
  As[0][lk + 3][lm] = (av0.w - mrow) * rrow;
  As[0][lk + 4][lm] = (av1.x - mrow) * rrow;
  As[0][lk + 5][lm] = (av1.y - mrow) * rrow;
  As[0][lk + 6][lm] = (av1.z - mrow) * rrow;
  As[0][lk + 7][lm] = (av1.w - mrow) * rrow;
  Bs[0][lk + 0][lm] = wv0.x; Bs[0][lk + 1][lm] = wv0.y;
  Bs[0][lk + 2][lm] = wv0.z; Bs[0][lk + 3][lm] = wv0.w;
  Bs[0][lk + 4][lm] = wv1.x; Bs[0][lk + 5][lm] = wv1.y;
  Bs[0][lk + 6][lm] = wv1.z; Bs[0][lk + 7][lm] = wv1.w;
  __syncthreads();

  for (int s = 0; s < 48; ++s) {
    const int buf = s & 1;
    if (s + 1 < 48) {
      const int k0 = (s + 1) * 16;
      av0 = *(const float4*)(arow + k0 + lk);
      av1 = *(const float4*)(arow + k0 + lk + 4);
      wv0 = *(const float4*)(wrow + k0 + lk);
      wv1 = *(const float4*)(wrow + k0 + lk + 4);
    }
#pragma unroll
    for (int kk = 0; kk < 16; ++kk) {
      float a[8], b[8];
      *(float4*)&a[0] = *(const float4*)&As[buf][kk][tm0];
      *(float4*)&a[4] = *(const float4*)&As[buf][kk][tm0 + 4];
      *(float4*)&b[0] = *(const float4*)&Bs[buf][kk][tn0];
      *(float4*)&b[4] = *(const float4*)&Bs[buf][kk][tn0 + 64];
#pragma unroll
      for (int i = 0; i < 8; ++i)
#pragma unroll
        for (int j = 0; j < 8; ++j) acc[i][j] += a[i] * b[j];
    }
    if (s + 1 < 48) {
      const int nb = buf ^ 1;
      As[nb][lk + 0][lm] = (av0.x - mrow) * rrow;
      As[nb][lk + 1][lm] = (av0.y - mrow) * rrow;
      As[nb][lk + 2][lm] = (av0.z - mrow) * rrow;
      As[nb][lk + 3][lm] = (av0.w - mrow) * rrow;
      As[nb][lk + 4][lm] = (av1.x - mrow) * rrow;
      As[nb][lk + 5][lm] = (av1.y - mrow) * rrow;
      As[nb][lk + 6][lm] = (av1.z - mrow) * rrow;
      As[nb][lk + 7][lm] = (av1.w - mrow) * rrow;
      Bs[nb][lk + 0][lm] = wv0.x; Bs[nb][lk + 1][lm] = wv0.y;
      Bs[nb][lk + 2][lm] = wv0.z; Bs[nb][lk + 3][lm] = wv0.w;
      Bs[nb][lk + 4][lm] = wv1.x; Bs[nb][lk + 5][lm] = wv1.y;
      Bs[nb][lk + 6][lm] = wv1.z; Bs[nb][lk + 7][lm] = wv1.w;
    }
    __syncthreads();
  }
#pragma unroll
  for (int i = 0; i < 8; ++i) {
    const int row = row0 + tm0 + i;
    float* cr = Cout + (size_t)row * 256 + wc0;
    const float* cc = cconst + coff + wc0;
    *(float4*)(cr + tn0) =
        make_float4(acc[i][0] + cc[tn0 + 0], acc[i][1] + cc[tn0 + 1],
                    acc[i][2] + cc[tn0 + 2], acc[i][3] + cc[tn0 + 3]);
    *(float4*)(cr + 64 + tn0) =
        make_float4(acc[i][4] + cc[64 + tn0 + 0], acc[i][5] + cc[64 + tn0 + 1],
                    acc[i][6] + cc[64 + tn0 + 2], acc[i][7] + cc[64 + tn0 + 3]);
  }
}

// -------- fused LN(slots) + q = LN @ Wgq^T + qconst. 64x64 tiles --------
__global__ LB void k_lnq(const float* __restrict__ slots,
                         const float* __restrict__ Wgq, const float* __restrict__ cconst,
                         float* __restrict__ qout) {
  __shared__ float As[16][64];
  __shared__ float Bs[16][64];
  __shared__ float mst[64], rst[64];
  const int row0 = blockIdx.x * 64;
  const int col0 = blockIdx.y * 64;
  const int t = threadIdx.x;
  // stats: 4 threads per row, 64 elems each
  {
    const int r = t >> 2, g = t & 3;
    const float* sr = slots + (size_t)(row0 + r) * 256 + g * 64;
    float s = 0.f, sq = 0.f;
#pragma unroll
    for (int m = 0; m < 16; ++m) {
      float4 v = *(const float4*)(sr + m * 4);
      s += v.x + v.y + v.z + v.w;
      sq += v.x * v.x + v.y * v.y + v.z * v.z + v.w * v.w;
    }
    s += __shfl_down(s, 2, 4); sq += __shfl_down(sq, 2, 4);
    s += __shfl_down(s, 1, 4); sq += __shfl_down(sq, 1, 4);
    if (g == 0) {
      float m = s * (1.f / 256.f);
      mst[r] = m;
      rst[r] = 1.f / sqrtf(sq * (1.f / 256.f) - m * m + LNEPS);
    }
  }
  __syncthreads();
  const int lm = t >> 2;
  const int lk = (t & 3) * 4;
  const int tm0 = (t >> 4) * 4;
  const int tn0 = (t & 15) * 4;
  const float mr = mst[lm], rr = rst[lm];
  const float* arow = slots + (size_t)(row0 + lm) * 256;
  const float* wrow = Wgq + (size_t)(col0 + lm) * 256;
  float acc[4][4] = {};
  for (int k0 = 0; k0 < 256; k0 += 16) {
    float4 av = *(const float4*)(arow + k0 + lk);
    float4 wv = *(const float4*)(wrow + k0 + lk);
    As[lk + 0][lm] = (av.x - mr) * rr;
    As[lk + 1][lm] = (av.y - mr) * rr;
    As[lk + 2][lm] = (av.z - mr) * rr;
    As[lk + 3][lm] = (av.w - mr) * rr;
    Bs[lk + 0][lm] = wv.x; Bs[lk + 1][lm] = wv.y;
    Bs[lk + 2][lm] = wv.z; Bs[lk + 3][lm] = wv.w;
    __syncthreads();
#pragma unroll
    for (int kk = 0; kk < 16; ++kk) {
      float a[4], b[4];
      *(float4*)a = *(const float4*)&As[kk][tm0];
      *(float4*)b = *(const float4*)&Bs[kk][tn0];
#pragma unroll
      for (int i = 0; i < 4; ++i)
#pragma unroll
        for (int j = 0; j < 4; ++j) acc[i][j] += a[i] * b[j];
    }
    __syncthreads();
  }
  const float* cc = cconst + 512 + col0 + tn0;
#pragma unroll
  for (int i = 0; i < 4; ++i) {
    *(float4*)(qout + (size_t)(row0 + tm0 + i) * 256 + col0 + tn0) =
        make_float4(acc[i][0] + cc[0], acc[i][1] + cc[1],
                    acc[i][2] + cc[2], acc[i][3] + cc[3]);
  }
}

// ---- dots = scale * q k^T, softmax over slots, write attn[b][h][i][j] ----
__global__ LB void k_dots(const float* __restrict__ q, const float* __restrict__ kmat,
                          float* __restrict__ attn) {
  const int blk = blockIdx.x;
  const int jc = blk & 3;
  const int h = (blk >> 2) & 3;
  const int b = blk >> 4;
  const int t = threadIdx.x;
  __shared__ float qs[NSLOT][DH];
  for (int l = t; l < NSLOT * DH; l += 256) {
    int i = l >> 6, d = l & 63;
    qs[i][d] = q[(size_t)(b * NSLOT + i) * 256 + h * 64 + d];
  }
  __syncthreads();
  const int j = jc * 256 + t;
  const float* kr = kmat + (size_t)(b * NFEAT + j) * 256 + h * 64;
  float acc[NSLOT] = {};
#pragma unroll
  for (int d4 = 0; d4 < DH; d4 += 4) {
    float4 kv = *(const float4*)(kr + d4);
#pragma unroll
    for (int i = 0; i < NSLOT; ++i)
      acc[i] += qs[i][d4] * kv.x + qs[i][d4 + 1] * kv.y + qs[i][d4 + 2] * kv.z + qs[i][d4 + 3] * kv.w;
  }
  float mx = -1e30f;
#pragma unroll
  for (int i = 0; i < NSLOT; ++i) { acc[i] *= QSCALE; mx = fmaxf(mx, acc[i]); }
  float s = 0.f;
#pragma unroll
  for (int i = 0; i < NSLOT; ++i) { acc[i] = expf(acc[i] - mx); s += acc[i]; }
  const float inv = 1.f / s;
  float* ab = attn + (size_t)(b * NH + h) * NSLOT * NFEAT + j;
#pragma unroll
  for (int i = 0; i < NSLOT; ++i) ab[(size_t)i * NFEAT] = acc[i] * inv;
}

// ---- upd[b,i,h,:] = sum_j (attn+eps) v / sum_j(attn+eps) ----
__global__ LB void k_upd(const float* __restrict__ attn, const float* __restrict__ vmat,
                         float* __restrict__ upd) {
  const int h = blockIdx.x & 3;
  const int b = blockIdx.x >> 2;
  const int t = threadIdx.x;
  __shared__ float at[NSLOT][64];
  __shared__ float vt[64][64];
  __shared__ float ssum[NSLOT];
  if (t < NSLOT) ssum[t] = 0.f;
  const int d = t & 63;
  const int ig = t >> 6;
  float acc[6] = {};
  const float* ab = attn + (size_t)(b * NH + h) * NSLOT * NFEAT;
  for (int j0 = 0; j0 < NFEAT; j0 += 64) {
    __syncthreads();
    for (int l = t; l < NSLOT * 64; l += 256) {
      int i = l >> 6, jj = l & 63;
      at[i][jj] = ab[(size_t)i * NFEAT + j0 + jj] + ATTN_EPS;
    }
#pragma unroll
    for (int r = 0; r < 4; ++r) {
      int l = r * 1024 + t * 4;
      int jj = l >> 6, dd = l & 63;
      *(float4*)&vt[jj][dd] = *(const float4*)(vmat + (size_t)(b * NFEAT + j0 + jj) * 256 + h * 64 + dd);
    }
    __syncthreads();
    if (t < NSLOT) {
      float s = 0.f;
      for (int jj = 0; jj < 64; ++jj) s += at[t][jj];
      ssum[t] += s;
    }
    for (int jj = 0; jj < 64; ++jj) {
      float vv = vt[jj][d];
#pragma unroll
      for (int u = 0; u < 6; ++u) acc[u] += at[ig * 6 + u][jj] * vv;
    }
  }
  __syncthreads();
#pragma unroll
  for (int u = 0; u < 6; ++u) {
    int i = ig * 6 + u;
    upd[(size_t)(b * NSLOT + i) * 256 + h * 64 + d] = acc[u] / ssum[i];
  }
}

// ---- fused GRU: gi = upd@Wih^T, gh = sprev@Whh^T, gru elementwise -> snext ----
// block: 16 rows x 64 dims, computes all 4 gate strips (r,z,i_n,h_n)
__global__ LB void k_grucat(const float* __restrict__ upd, const float* __restrict__ sprev,
                            const float* __restrict__ Wih, const float* __restrict__ Whh,
                            const float* __restrict__ bih, const float* __restrict__ bhh,
                            float* __restrict__ snext) {
  __shared__ float As[16][17];
  __shared__ float Bs[3][16][65];
  const int row0 = blockIdx.x * 16;
  const int d0 = blockIdx.y * 64;
  const int t = threadIdx.x;
  const int r = t >> 4;            // compute row 0..15 (also A-stage row)
  const int lk = t & 15;           // A-stage k
  const int d4 = (t & 15) * 4;     // compute dim base
  const int bc = t >> 2;           // B-stage dim 0..63
  const int bk4 = (t & 3) * 4;     // B-stage k float4
  float accR[4] = {}, accZ[4] = {}, accN[4] = {}, accH[4] = {};

  // phase A: upd @ Wih rows {d, 256+d, 512+d}
  for (int k0 = 0; k0 < 256; k0 += 16) {
    As[lk][r] = upd[(size_t)(row0 + r) * 256 + k0 + lk];
#pragma unroll
    for (int s = 0; s < 3; ++s) {
      float4 w = *(const float4*)(Wih + (size_t)(s * 256 + d0 + bc) * 256 + k0 + bk4);
      Bs[s][bk4 + 0][bc] = w.x; Bs[s][bk4 + 1][bc] = w.y;
      Bs[s][bk4 + 2][bc] = w.z; Bs[s][bk4 + 3][bc] = w.w;
    }
    __syncthreads();
#pragma unroll
    for (int kk = 0; kk < 16; ++kk) {
      float a = As[kk][r];
#pragma unroll
      for (int x = 0; x < 4; ++x) {
        accR[x] += a * Bs[0][kk][d4 + x];
        accZ[x] += a * Bs[1][kk][d4 + x];
        accN[x] += a * Bs[2][kk][d4 + x];
      }
    }
    __syncthreads();
  }
  // phase B: sprev @ Whh rows {d, 256+d, 512+d}
  for (int k0 = 0; k0 < 256; k0 += 16) {
    As[lk][r] = sprev[(size_t)(row0 + r) * 256 + k0 + lk];
#pragma unroll
    for (int s = 0; s < 3; ++s) {
      float4 w = *(const float4*)(Whh + (size_t)(s * 256 + d0 + bc) * 256 + k0 + bk4);
      Bs[s][bk4 + 0][bc] = w.x; Bs[s][bk4 + 1][bc] = w.y;
      Bs[s][bk4 + 2][bc] = w.z; Bs[s][bk4 + 3][bc] = w.w;
    }
    __syncthreads();
#pragma unroll
    for (int kk = 0; kk < 16; ++kk) {
      float a = As[kk][r];
#pragma unroll
      for (int x = 0; x < 4; ++x) {
        accR[x] += a * Bs[0][kk][d4 + x];
        accZ[x] += a * Bs[1][kk][d4 + x];
        accH[x] += a * Bs[2][kk][d4 + x];
      }
    }
    __syncthreads();
  }
  // epilogue: GRU
  const int row = row0 + r;
  float4 hp = *(const float4*)(sprev + (size_t)row * 256 + d0 + d4);
  const float hpv[4] = {hp.x, hp.y, hp.z, hp.w};
  float out[4];
#pragma unroll
  for (int x = 0; x < 4; ++x) {
    const int dd = d0 + d4 + x;
    float rr = 1.f / (1.f + expf(-(accR[x] + bih[dd] + bhh[dd])));
    float zz = 1.f / (1.f + expf(-(accZ[x] + bih[256 + dd] + bhh[256 + dd])));
    float nn = tanhf(accN[x] + bih[512 + dd] + rr * (accH[x] + bhh[512 + dd]));
    out[x] = (1.f - zz) * nn + zz * hpv[x];
  }
  *(float4*)(snext + (size_t)row * 256 + d0 + d4) = make_float4(out[0], out[1], out[2], out[3]);
}

// ---------------- attn_vis = mean over heads ----------------
__global__ LB void k_attnvis(const float* __restrict__ attn, float* __restrict__ out) {
  const int idx = blockIdx.x * 256 + threadIdx.x;
  const int j = idx & 1023;
  const int rem = idx >> 10;
  const int i = rem % NSLOT;
  const int b = rem / NSLOT;
  float s = 0.f;
#pragma unroll
  for (int h = 0; h < NH; ++h)
    s += attn[(size_t)((b * NH + h) * NSLOT + i) * NFEAT + j];
  out[idx] = 0.25f * s;
}

// ---- VQ argmin (ref formula) + straight-through in-place ----
__global__ LB void k_vq(float* __restrict__ slots, const float* __restrict__ cb,
                        float* __restrict__ idx_out, float* __restrict__ bestd2) {
  const int r = blockIdx.x;
  const int t = threadIdx.x;
  __shared__ float xs[256];
  __shared__ float red[256];
  __shared__ float rv[256];
  __shared__ int ri[256];
  xs[t] = slots[(size_t)r * 256 + t];
  __syncthreads();
  red[t] = xs[t] * xs[t]; __syncthreads();
  for (int o = 128; o > 0; o >>= 1) { if (t < o) red[t] += red[t + o]; __syncthreads(); }
  const float x2 = red[0];
  float best = 1e30f; int bidx = 0;
#pragma unroll
  for (int cset = 0; cset < 2; ++cset) {
    const int c = cset * 256 + t;
    const float* cr = cb + (size_t)c * 256;
    float xc = 0.f, cc = 0.f;
    for (int dd = 0; dd < 256; dd += 4) {
      float4 cv = *(const float4*)(cr + dd);
      xc += xs[dd] * cv.x + xs[dd + 1] * cv.y + xs[dd + 2] * cv.z + xs[dd + 3] * cv.w;
      cc += cv.x * cv.x + cv.y * cv.y + cv.z * cv.z + cv.w * cv.w;
    }
    float d2 = x2 - 2.f * xc + cc;
    if (d2 < best) { best = d2; bidx = c; }
  }
  rv[t] = best; ri[t] = bidx; __syncthreads();
  for (int o = 128; o > 0; o >>= 1) {
    if (t < o) {
      if (rv[t + o] < rv[t] || (rv[t + o] == rv[t] && ri[t + o] < ri[t])) {
        rv[t] = rv[t + o]; ri[t] = ri[t + o];
      }
    }
    __syncthreads();
  }
  const int wi = ri[0];
  const float cval = cb[(size_t)wi * 256 + t];
  const float diff = xs[t] - cval;
  red[t] = diff * diff; __syncthreads();
  for (int o = 128; o > 0; o >>= 1) { if (t < o) red[t] += red[t + o]; __syncthreads(); }
  if (t == 0) { idx_out[r] = (float)wi; bestd2[r] = red[0]; }
  slots[(size_t)r * 256 + t] = cval;
}

__global__ LB void k_commit(const float* __restrict__ bestd2, float* __restrict__ out) {
  const int t = threadIdx.x;
  __shared__ float red[256];
  float s = 0.f;
  for (int i = t; i < MS; i += 256) s += bestd2[i];
  red[t] = s; __syncthreads();
  for (int o = 128; o > 0; o >>= 1) { if (t < o) red[t] += red[t + o]; __syncthreads(); }
  if (t == 0) out[0] = red[0] / (float)(MS * 256);
}

__global__ LB void k_copy(const float* __restrict__ src, float* __restrict__ dst) {
  const int i = blockIdx.x * 256 + threadIdx.x;
  dst[i] = src[i];
}

extern "C" void kernel_launch(void* const* d_in, const int* in_sizes, int n_in,
                              void* d_out, int out_size, void* d_ws, size_t ws_size,
                              hipStream_t stream) {
  const float* features = (const float*)d_in[0];
  const float* cond = (const float*)d_in[1];
  const float* Wq = (const float*)d_in[2];
  const float* Wk = (const float*)d_in[3];
  const float* Wv = (const float*)d_in[4];
  const float* g_in = (const float*)d_in[5];
  const float* b_in = (const float*)d_in[6];
  const float* g_s = (const float*)d_in[7];
  const float* b_s = (const float*)d_in[8];
  const float* Wih = (const float*)d_in[9];
  const float* Whh = (const float*)d_in[10];
  const float* bih = (const float*)d_in[11];
  const float* bhh = (const float*)d_in[12];
  const float* cb = (const float*)d_in[13];
  float* out = (float*)d_out;

  float* ws = (float*)d_ws;
  float* stats = ws;  ws += 2 * MF;
  float* kbuf = ws;   ws += (size_t)MF * 256;
  float* vbuf = ws;   ws += (size_t)MF * 256;
  float* attn = ws;   ws += (size_t)BATCH * NH * NSLOT * NFEAT;
  float* qbuf = ws;   ws += (size_t)MS * 256;
  float* sbufA = ws;  ws += (size_t)MS * 256;
  float* sbufB = ws;  ws += (size_t)MS * 256;
  float* updb = ws;   ws += (size_t)MS * 256;
  float* Wgk = ws;    ws += 256 * FDIM;
  float* Wgv = ws;    ws += 256 * FDIM;
  float* Wgq = ws;    ws += 256 * 256;
  float* cconst = ws; ws += 768;
  float* bestd2 = ws; ws += MS;

  float* out_slots = out;
  float* out_post = out + 196608;
  float* out_pre = out + 196608 + 786432;
  float* out_idx = out + 196608 + 786432 * 2;
  float* out_commit = out_idx + 768;

  hipMemcpyAsync(sbufA, cond, (size_t)MS * 256 * sizeof(float),
                 hipMemcpyDeviceToDevice, stream);

  k_prep<<<768, 256, 0, stream>>>(Wk, Wv, Wq, g_in, b_in, g_s, b_s, Wgk, Wgv, Wgq, cconst);
  k_rowstats<<<MF / 4, 256, 0, stream>>>(features, stats);
  k_lnkv<<<dim3(MF / 128, 4), 256, 0, stream>>>(features, stats, Wgk, Wgv, cconst, kbuf, vbuf);

  float* scur = sbufA;
  float* snxt = sbufB;
  for (int call = 0; call < 2; ++call) {
    for (int it = 0; it < NITER; ++it) {
      k_lnq<<<dim3(MS / 64, 4), 256, 0, stream>>>(scur, Wgq, cconst, qbuf);
      k_dots<<<BATCH * NH * 4, 256, 0, stream>>>(qbuf, kbuf, attn);
      k_upd<<<BATCH * NH, 256, 0, stream>>>(attn, vbuf, updb);
      k_grucat<<<dim3(MS / 16, 4), 256, 0, stream>>>(updb, scur, Wih, Whh, bih, bhh, snxt);
      float* tmp = scur; scur = snxt; snxt = tmp;
    }
    k_attnvis<<<BATCH * NSLOT * NFEAT / 256, 256, 0, stream>>>(attn, call ? out_post : out_pre);
    if (call == 0) {
      k_vq<<<MS, 256, 0, stream>>>(scur, cb, out_idx, bestd2);
      k_commit<<<1, 256, 0, stream>>>(bestd2, out_commit);
    }
  }
  k_copy<<<MS, 256, 0, stream>>>(scur, out_slots);
}

// Round 3
// 1110.411 us; speedup vs baseline: 6.0542x; 6.0542x over previous
//
#include <hip/hip_runtime.h>
#include <math.h>

#define LB __launch_bounds__(256)

constexpr int BATCH = 32, NFEAT = 1024, FDIM = 768, NSLOT = 24;
constexpr int NH = 4, DH = 64, NITER = 3;
constexpr int MF = BATCH * NFEAT;   // 32768 feature rows
constexpr int MS = BATCH * NSLOT;   // 768 slot rows
constexpr float QSCALE = 0.125f;    // dh^-0.5
constexpr float ATTN_EPS = 1e-8f;
constexpr float LNEPS = 1e-5f;

// ---- prep: Wg = W * gamma (over k), cconst[c] = sum_k beta[k]*W[c][k] ----
__global__ LB void k_prep(const float* __restrict__ Wk, const float* __restrict__ Wv,
                          const float* __restrict__ Wq,
                          const float* __restrict__ g_in, const float* __restrict__ b_in,
                          const float* __restrict__ g_s, const float* __restrict__ b_s,
                          float* __restrict__ Wgk, float* __restrict__ Wgv,
                          float* __restrict__ Wgq, float* __restrict__ cconst) {
  const int r = blockIdx.x;
  const int t = threadIdx.x;
  const float* src; float* dst; const float* g; const float* bb; int len;
  if (r < 256)      { src = Wk + (size_t)r * FDIM;         dst = Wgk + (size_t)r * FDIM;         g = g_in; bb = b_in; len = FDIM; }
  else if (r < 512) { src = Wv + (size_t)(r - 256) * FDIM; dst = Wgv + (size_t)(r - 256) * FDIM; g = g_in; bb = b_in; len = FDIM; }
  else              { src = Wq + (size_t)(r - 512) * 256;  dst = Wgq + (size_t)(r - 512) * 256;  g = g_s;  bb = b_s;  len = 256; }
  float s = 0.f;
  for (int k = t; k < len; k += 256) { float w = src[k]; dst[k] = w * g[k]; s += bb[k] * w; }
  __shared__ float red[256];
  red[t] = s; __syncthreads();
  for (int o = 128; o > 0; o >>= 1) { if (t < o) red[t] += red[t + o]; __syncthreads(); }
  if (t == 0) cconst[r] = red[0];
}

// ---------------- per-row mean/rstd of features ----------------
__global__ LB void k_rowstats(const float* __restrict__ x, float* __restrict__ stats) {
  const int row = blockIdx.x * 4 + (threadIdx.x >> 6);
  const int lane = threadIdx.x & 63;
  const float* xr = x + (size_t)row * FDIM;
  float s = 0.f, sq = 0.f;
#pragma unroll
  for (int i = 0; i < 3; ++i) {
    float4 v = *(const float4*)(xr + i * 256 + lane * 4);
    s += v.x + v.y + v.z + v.w;
    sq += v.x * v.x + v.y * v.y + v.z * v.z + v.w * v.w;
  }
#pragma unroll
  for (int o = 32; o > 0; o >>= 1) { s += __shfl_down(s, o, 64); sq += __shfl_down(sq, o, 64); }
  if (lane == 0) {
    float m = s / (float)FDIM;
    float var = sq / (float)FDIM - m * m;
    stats[row * 2] = m;
    stats[row * 2 + 1] = 1.f / sqrtf(var + LNEPS);
  }
}

// -------- fused LN(features) @ Wg^T -> k,v. 128x128 tiles, BK=16, reg-prefetch dbuf --------
// NOTE: plain LB(256) — an occupancy bound here forced a 20 GB scratch spill in r2.
__global__ LB void k_lnkv(
    const float* __restrict__ x, const float* __restrict__ stats,
    const float* __restrict__ Wgk, const float* __restrict__ Wgv,
    const float* __restrict__ cconst,
    float* __restrict__ kout, float* __restrict__ vout) {
  __shared__ float As[2][16][128];
  __shared__ float Bs[2][16][128];
  const int row0 = blockIdx.x * 128;
  const int col0 = blockIdx.y * 128;       // 0,128 -> k ; 256,384 -> v
  const float* W = (col0 < 256) ? Wgk : Wgv;
  float* Cout = (col0 < 256) ? kout : vout;
  const int coff = (col0 < 256) ? 0 : 256;
  const int wc0 = col0 & 255;
  const int t = threadIdx.x;
  const int lm = t >> 1;                    // staging row 0..127
  const int lk = (t & 1) * 8;               // 0 or 8
  const int tm0 = (t >> 4) * 8;             // 8 output rows
  const int tn0 = (t & 15) * 4;             // col strips at +0, +64 (conflict-free)
  const float mrow = stats[(row0 + lm) * 2];
  const float rrow = stats[(row0 + lm) * 2 + 1];
  const float* arow = x + (size_t)(row0 + lm) * FDIM;
  const float* wrow = W + (size_t)(wc0 + lm) * FDIM;
  float acc[8][8] = {};
  float4 av0, av1, wv0, wv1;

  av0 = *(const float4*)(arow + lk);
  av1 = *(const float4*)(arow + lk + 4);
  wv0 = *(const float4*)(wrow + lk);
  wv1 = *(const float4*)(wrow + lk + 4);
  As[0][lk + 0][lm] = (av0.x - mrow) * rrow;
  As[0][lk + 1][lm] = (av0.y - mrow) * rrow;
  As[0][lk + 2][lm] = (av0.z - mrow) * rrow;
  As[0][lk + 3][lm] = (av0.w - mrow) * rrow;
  As[0][lk + 4][lm] = (av1.x - mrow) * rrow;
  As[0][lk + 5][lm] = (av1.y - mrow) * rrow;
  As[0][lk + 6][lm] = (av1.z - mrow) * rrow;
  As[0][lk + 7][lm] = (av1.w - mrow) * rrow;
  Bs[0][lk + 0][lm] = wv0.x; Bs[0][lk + 1][lm] = wv0.y;
  Bs[0][lk + 2][lm] = wv0.z; Bs[0][lk + 3][lm] = wv0.w;
  Bs[0][lk + 4][lm] = wv1.x; Bs[0][lk + 5][lm] = wv1.y;
  Bs[0][lk + 6][lm] = wv1.z; Bs[0][lk + 7][lm] = wv1.w;
  __syncthreads();

  for (int s = 0; s < 48; ++s) {
    const int buf = s & 1;
    if (s + 1 < 48) {
      const int k0 = (s + 1) * 16;
      av0 = *(const float4*)(arow + k0 + lk);
      av1 = *(const float4*)(arow + k0 + lk + 4);
      wv0 = *(const float4*)(wrow + k0 + lk);
      wv1 = *(const float4*)(wrow + k0 + lk + 4);
    }
#pragma unroll
    for (int kk = 0; kk < 16; ++kk) {
      float a[8], b[8];
      *(float4*)&a[0] = *(const float4*)&As[buf][kk][tm0];
      *(float4*)&a[4] = *(const float4*)&As[buf][kk][tm0 + 4];
      *(float4*)&b[0] = *(const float4*)&Bs[buf][kk][tn0];
      *(float4*)&b[4] = *(const float4*)&Bs[buf][kk][tn0 + 64];
#pragma unroll
      for (int i = 0; i < 8; ++i)
#pragma unroll
        for (int j = 0; j < 8; ++j) acc[i][j] += a[i] * b[j];
    }
    if (s + 1 < 48) {
      const int nb = buf ^ 1;
      As[nb][lk + 0][lm] = (av0.x - mrow) * rrow;
      As[nb][lk + 1][lm] = (av0.y - mrow) * rrow;
      As[nb][lk + 2][lm] = (av0.z - mrow) * rrow;
      As[nb][lk + 3][lm] = (av0.w - mrow) * rrow;
      As[nb][lk + 4][lm] = (av1.x - mrow) * rrow;
      As[nb][lk + 5][lm] = (av1.y - mrow) * rrow;
      As[nb][lk + 6][lm] = (av1.z - mrow) * rrow;
      As[nb][lk + 7][lm] = (av1.w - mrow) * rrow;
      Bs[nb][lk + 0][lm] = wv0.x; Bs[nb][lk + 1][lm] = wv0.y;
      Bs[nb][lk + 2][lm] = wv0.z; Bs[nb][lk + 3][lm] = wv0.w;
      Bs[nb][lk + 4][lm] = wv1.x; Bs[nb][lk + 5][lm] = wv1.y;
      Bs[nb][lk + 6][lm] = wv1.z; Bs[nb][lk + 7][lm] = wv1.w;
    }
    __syncthreads();
  }
#pragma unroll
  for (int i = 0; i < 8; ++i) {
    const int row = row0 + tm0 + i;
    float* cr = Cout + (size_t)row * 256 + wc0;
    const float* cc = cconst + coff + wc0;
    *(float4*)(cr + tn0) =
        make_float4(acc[i][0] + cc[tn0 + 0], acc[i][1] + cc[tn0 + 1],
                    acc[i][2] + cc[tn0 + 2], acc[i][3] + cc[tn0 + 3]);
    *(float4*)(cr + 64 + tn0) =
        make_float4(acc[i][4] + cc[64 + tn0 + 0], acc[i][5] + cc[64 + tn0 + 1],
                    acc[i][6] + cc[64 + tn0 + 2], acc[i][7] + cc[64 + tn0 + 3]);
  }
}

// -------- fused LN(slots) + q = LN @ Wgq^T + qconst. 64x64 tiles --------
__global__ LB void k_lnq(const float* __restrict__ slots,
                         const float* __restrict__ Wgq, const float* __restrict__ cconst,
                         float* __restrict__ qout) {
  __shared__ float As[16][64];
  __shared__ float Bs[16][64];
  __shared__ float mst[64], rst[64];
  const int row0 = blockIdx.x * 64;
  const int col0 = blockIdx.y * 64;
  const int t = threadIdx.x;
  {
    const int r = t >> 2, g = t & 3;
    const float* sr = slots + (size_t)(row0 + r) * 256 + g * 64;
    float s = 0.f, sq = 0.f;
#pragma unroll
    for (int m = 0; m < 16; ++m) {
      float4 v = *(const float4*)(sr + m * 4);
      s += v.x + v.y + v.z + v.w;
      sq += v.x * v.x + v.y * v.y + v.z * v.z + v.w * v.w;
    }
    s += __shfl_down(s, 2, 4); sq += __shfl_down(sq, 2, 4);
    s += __shfl_down(s, 1, 4); sq += __shfl_down(sq, 1, 4);
    if (g == 0) {
      float m = s * (1.f / 256.f);
      mst[r] = m;
      rst[r] = 1.f / sqrtf(sq * (1.f / 256.f) - m * m + LNEPS);
    }
  }
  __syncthreads();
  const int lm = t >> 2;
  const int lk = (t & 3) * 4;
  const int tm0 = (t >> 4) * 4;
  const int tn0 = (t & 15) * 4;
  const float mr = mst[lm], rr = rst[lm];
  const float* arow = slots + (size_t)(row0 + lm) * 256;
  const float* wrow = Wgq + (size_t)(col0 + lm) * 256;
  float acc[4][4] = {};
  for (int k0 = 0; k0 < 256; k0 += 16) {
    float4 av = *(const float4*)(arow + k0 + lk);
    float4 wv = *(const float4*)(wrow + k0 + lk);
    As[lk + 0][lm] = (av.x - mr) * rr;
    As[lk + 1][lm] = (av.y - mr) * rr;
    As[lk + 2][lm] = (av.z - mr) * rr;
    As[lk + 3][lm] = (av.w - mr) * rr;
    Bs[lk + 0][lm] = wv.x; Bs[lk + 1][lm] = wv.y;
    Bs[lk + 2][lm] = wv.z; Bs[lk + 3][lm] = wv.w;
    __syncthreads();
#pragma unroll
    for (int kk = 0; kk < 16; ++kk) {
      float a[4], b[4];
      *(float4*)a = *(const float4*)&As[kk][tm0];
      *(float4*)b = *(const float4*)&Bs[kk][tn0];
#pragma unroll
      for (int i = 0; i < 4; ++i)
#pragma unroll
        for (int j = 0; j < 4; ++j) acc[i][j] += a[i] * b[j];
    }
    __syncthreads();
  }
  const float* cc = cconst + 512 + col0 + tn0;
#pragma unroll
  for (int i = 0; i < 4; ++i) {
    *(float4*)(qout + (size_t)(row0 + tm0 + i) * 256 + col0 + tn0) =
        make_float4(acc[i][0] + cc[0], acc[i][1] + cc[1],
                    acc[i][2] + cc[2], acc[i][3] + cc[3]);
  }
}

// ---- fused: dots -> softmax(over slots) -> (attn+eps) partial-sums + partial V-mix ----
// grid (b,h,jc): 512 blocks. Thread owns j = jc*256 + t. Partials per jc chunk;
// finalize kernel combines 4 chunks. attn materialized only when WRITE_ATTN.
template <bool WRITE_ATTN>
__global__ LB void k_fdots(const float* __restrict__ q, const float* __restrict__ kmat,
                           const float* __restrict__ vmat, float* __restrict__ attn,
                           float* __restrict__ updp, float* __restrict__ ssump) {
  const int blk = blockIdx.x;
  const int jc = blk & 3;
  const int h = (blk >> 2) & 3;
  const int b = blk >> 4;
  const int t = threadIdx.x;
  __shared__ float qs[NSLOT][DH];     // 6 KB
  __shared__ float at[NSLOT][256];    // 24 KB
  __shared__ float vt[DH][DH];        // 16 KB
  __shared__ float ssr[NSLOT][8];
  for (int l = t; l < NSLOT * DH; l += 256) {
    int i = l >> 6, d = l & 63;
    qs[i][d] = q[(size_t)(b * NSLOT + i) * 256 + h * 64 + d];
  }
  __syncthreads();
  const int j = jc * 256 + t;
  const float* kr = kmat + (size_t)(b * NFEAT + j) * 256 + h * 64;
  float acc[NSLOT] = {};
#pragma unroll
  for (int d4 = 0; d4 < DH; d4 += 4) {
    float4 kv = *(const float4*)(kr + d4);
#pragma unroll
    for (int i = 0; i < NSLOT; ++i) {
      float4 qv = *(const float4*)&qs[i][d4];
      acc[i] += qv.x * kv.x + qv.y * kv.y + qv.z * kv.z + qv.w * kv.w;
    }
  }
  float mx = -1e30f;
#pragma unroll
  for (int i = 0; i < NSLOT; ++i) { acc[i] *= QSCALE; mx = fmaxf(mx, acc[i]); }
  float s = 0.f;
#pragma unroll
  for (int i = 0; i < NSLOT; ++i) { acc[i] = expf(acc[i] - mx); s += acc[i]; }
  const float inv = 1.f / s;
  float* ab = attn + (size_t)(b * NH + h) * NSLOT * NFEAT + j;
#pragma unroll
  for (int i = 0; i < NSLOT; ++i) {
    const float w = acc[i] * inv;
    if (WRITE_ATTN) ab[(size_t)i * NFEAT] = w;
    at[i][t] = w + ATTN_EPS;
  }
  __syncthreads();
  // partial row sums of (attn+eps), rotated access to dodge bank conflicts
  if (t < 192) {
    const int i = t >> 3, s8 = t & 7;
    float sp = 0.f;
#pragma unroll
    for (int m = 0; m < 32; ++m) sp += at[i][s8 * 32 + ((m + t) & 31)];
    ssr[i][s8] = sp;
  }
  // V mix: acc2[u] = sum_j at[ig*6+u][j] * v[j][d]
  const int d = t & 63;
  const int ig = t >> 6;
  float acc2[6] = {};
  for (int j0 = 0; j0 < 256; j0 += 64) {
    __syncthreads();
#pragma unroll
    for (int rl = 0; rl < 4; ++rl) {
      const int l = rl * 1024 + t * 4;
      const int jj = l >> 6, dd = l & 63;
      *(float4*)&vt[jj][dd] =
          *(const float4*)(vmat + (size_t)(b * NFEAT + jc * 256 + j0 + jj) * 256 + h * 64 + dd);
    }
    __syncthreads();
#pragma unroll 16
    for (int jj = 0; jj < 64; ++jj) {
      const float vv = vt[jj][d];
#pragma unroll
      for (int u = 0; u < 6; ++u) acc2[u] += at[ig * 6 + u][j0 + jj] * vv;
    }
  }
  __syncthreads();
  if (t < NSLOT) {
    float sp = 0.f;
#pragma unroll
    for (int u = 0; u < 8; ++u) sp += ssr[t][u];
    ssump[((size_t)(b * NH + h) * 4 + jc) * NSLOT + t] = sp;
  }
  float* up = updp + (((size_t)(b * NH + h) * 4 + jc) * NSLOT) * 64;
#pragma unroll
  for (int u = 0; u < 6; ++u) up[(ig * 6 + u) * 64 + d] = acc2[u];
}

// ---- finalize: upd = (sum_jc updp) / (sum_jc ssump), layout [b][i][h][d] ----
__global__ LB void k_updfin(const float* __restrict__ updp, const float* __restrict__ ssump,
                            float* __restrict__ upd) {
  const int gid = blockIdx.x * 256 + threadIdx.x;
  const int d = gid & 63;
  const int h = (gid >> 6) & 3;
  const int rem = gid >> 8;   // b*24 + i
  const int i = rem % 24;
  const int b = rem / 24;
  float s = 0.f, w = 0.f;
#pragma unroll
  for (int jc = 0; jc < 4; ++jc) {
    const size_t base = (size_t)(b * NH + h) * 4 + jc;
    s += updp[base * NSLOT * 64 + i * 64 + d];
    w += ssump[base * NSLOT + i];
  }
  upd[gid] = s / w;
}

// ---- fused GRU: 8-row x 64-dim tiles (384 blocks), both GEMMs + elementwise ----
__global__ LB void k_grucat(const float* __restrict__ upd, const float* __restrict__ sprev,
                            const float* __restrict__ Wih, const float* __restrict__ Whh,
                            const float* __restrict__ bih, const float* __restrict__ bhh,
                            float* __restrict__ snext) {
  __shared__ float As[16][8];
  __shared__ float Bs[3][16][66];
  const int row0 = blockIdx.x * 8;
  const int d0 = blockIdx.y * 64;
  const int t = threadIdx.x;
  const int r = t >> 5;            // 0..7
  const int dd = (t & 31) * 2;     // dims dd, dd+1
  const int bc = t >> 2;           // 0..63
  const int bk4 = (t & 3) * 4;
  float accR[2] = {}, accZ[2] = {}, accN[2] = {}, accH[2] = {};
  // phase A: upd @ Wih (strips r,z,n)
  for (int k0 = 0; k0 < 256; k0 += 16) {
    if (t < 128) As[t & 15][t >> 4] = upd[(size_t)(row0 + (t >> 4)) * 256 + k0 + (t & 15)];
#pragma unroll
    for (int s = 0; s < 3; ++s) {
      float4 w = *(const float4*)(Wih + (size_t)(s * 256 + d0 + bc) * 256 + k0 + bk4);
      Bs[s][bk4 + 0][bc] = w.x; Bs[s][bk4 + 1][bc] = w.y;
      Bs[s][bk4 + 2][bc] = w.z; Bs[s][bk4 + 3][bc] = w.w;
    }
    __syncthreads();
#pragma unroll
    for (int kk = 0; kk < 16; ++kk) {
      const float a = As[kk][r];
      const float2 b0 = *(const float2*)&Bs[0][kk][dd];
      const float2 b1 = *(const float2*)&Bs[1][kk][dd];
      const float2 b2 = *(const float2*)&Bs[2][kk][dd];
      accR[0] += a * b0.x; accR[1] += a * b0.y;
      accZ[0] += a * b1.x; accZ[1] += a * b1.y;
      accN[0] += a * b2.x; accN[1] += a * b2.y;
    }
    __syncthreads();
  }
  // phase B: sprev @ Whh (strips r,z,h)
  for (int k0 = 0; k0 < 256; k0 += 16) {
    if (t < 128) As[t & 15][t >> 4] = sprev[(size_t)(row0 + (t >> 4)) * 256 + k0 + (t & 15)];
#pragma unroll
    for (int s = 0; s < 3; ++s) {
      float4 w = *(const float4*)(Whh + (size_t)(s * 256 + d0 + bc) * 256 + k0 + bk4);
      Bs[s][bk4 + 0][bc] = w.x; Bs[s][bk4 + 1][bc] = w.y;
      Bs[s][bk4 + 2][bc] = w.z; Bs[s][bk4 + 3][bc] = w.w;
    }
    __syncthreads();
#pragma unroll
    for (int kk = 0; kk < 16; ++kk) {
      const float a = As[kk][r];
      const float2 b0 = *(const float2*)&Bs[0][kk][dd];
      const float2 b1 = *(const float2*)&Bs[1][kk][dd];
      const float2 b2 = *(const float2*)&Bs[2][kk][dd];
      accR[0] += a * b0.x; accR[1] += a * b0.y;
      accZ[0] += a * b1.x; accZ[1] += a * b1.y;
      accH[0] += a * b2.x; accH[1] += a * b2.y;
    }
    __syncthreads();
  }
  const int row = row0 + r;
  const float2 hp = *(const float2*)(sprev + (size_t)row * 256 + d0 + dd);
  const float hpv[2] = {hp.x, hp.y};
  float o[2];
#pragma unroll
  for (int x = 0; x < 2; ++x) {
    const int c = d0 + dd + x;
    const float rr = 1.f / (1.f + expf(-(accR[x] + bih[c] + bhh[c])));
    const float zz = 1.f / (1.f + expf(-(accZ[x] + bih[256 + c] + bhh[256 + c])));
    const float nn = tanhf(accN[x] + bih[512 + c] + rr * (accH[x] + bhh[512 + c]));
    o[x] = (1.f - zz) * nn + zz * hpv[x];
  }
  *(float2*)(snext + (size_t)row * 256 + d0 + dd) = make_float2(o[0], o[1]);
}

// ---------------- attn_vis = mean over heads ----------------
__global__ LB void k_attnvis(const float* __restrict__ attn, float* __restrict__ out) {
  const int idx = blockIdx.x * 256 + threadIdx.x;
  const int j = idx & 1023;
  const int rem = idx >> 10;
  const int i = rem % NSLOT;
  const int b = rem / NSLOT;
  float s = 0.f;
#pragma unroll
  for (int h = 0; h < NH; ++h)
    s += attn[(size_t)((b * NH + h) * NSLOT + i) * NFEAT + j];
  out[idx] = 0.25f * s;
}

// ---- VQ argmin (ref formula) + straight-through in-place ----
__global__ LB void k_vq(float* __restrict__ slots, const float* __restrict__ cb,
                        float* __restrict__ idx_out, float* __restrict__ bestd2) {
  const int r = blockIdx.x;
  const int t = threadIdx.x;
  __shared__ float xs[256];
  __shared__ float red[256];
  __shared__ float rv[256];
  __shared__ int ri[256];
  xs[t] = slots[(size_t)r * 256 + t];
  __syncthreads();
  red[t] = xs[t] * xs[t]; __syncthreads();
  for (int o = 128; o > 0; o >>= 1) { if (t < o) red[t] += red[t + o]; __syncthreads(); }
  const float x2 = red[0];
  float best = 1e30f; int bidx = 0;
#pragma unroll
  for (int cset = 0; cset < 2; ++cset) {
    const int c = cset * 256 + t;
    const float* cr = cb + (size_t)c * 256;
    float xc = 0.f, cc = 0.f;
    for (int dd = 0; dd < 256; dd += 4) {
      float4 cv = *(const float4*)(cr + dd);
      xc += xs[dd] * cv.x + xs[dd + 1] * cv.y + xs[dd + 2] * cv.z + xs[dd + 3] * cv.w;
      cc += cv.x * cv.x + cv.y * cv.y + cv.z * cv.z + cv.w * cv.w;
    }
    float d2 = x2 - 2.f * xc + cc;
    if (d2 < best) { best = d2; bidx = c; }
  }
  rv[t] = best; ri[t] = bidx; __syncthreads();
  for (int o = 128; o > 0; o >>= 1) {
    if (t < o) {
      if (rv[t + o] < rv[t] || (rv[t + o] == rv[t] && ri[t + o] < ri[t])) {
        rv[t] = rv[t + o]; ri[t] = ri[t + o];
      }
    }
    __syncthreads();
  }
  const int wi = ri[0];
  const float cval = cb[(size_t)wi * 256 + t];
  const float diff = xs[t] - cval;
  red[t] = diff * diff; __syncthreads();
  for (int o = 128; o > 0; o >>= 1) { if (t < o) red[t] += red[t + o]; __syncthreads(); }
  if (t == 0) { idx_out[r] = (float)wi; bestd2[r] = red[0]; }
  slots[(size_t)r * 256 + t] = cval;
}

__global__ LB void k_commit(const float* __restrict__ bestd2, float* __restrict__ out) {
  const int t = threadIdx.x;
  __shared__ float red[256];
  float s = 0.f;
  for (int i = t; i < MS; i += 256) s += bestd2[i];
  red[t] = s; __syncthreads();
  for (int o = 128; o > 0; o >>= 1) { if (t < o) red[t] += red[t + o]; __syncthreads(); }
  if (t == 0) out[0] = red[0] / (float)(MS * 256);
}

__global__ LB void k_copy(const float* __restrict__ src, float* __restrict__ dst) {
  const int i = blockIdx.x * 256 + threadIdx.x;
  dst[i] = src[i];
}

extern "C" void kernel_launch(void* const* d_in, const int* in_sizes, int n_in,
                              void* d_out, int out_size, void* d_ws, size_t ws_size,
                              hipStream_t stream) {
  const float* features = (const float*)d_in[0];
  const float* cond = (const float*)d_in[1];
  const float* Wq = (const float*)d_in[2];
  const float* Wk = (const float*)d_in[3];
  const float* Wv = (const float*)d_in[4];
  const float* g_in = (const float*)d_in[5];
  const float* b_in = (const float*)d_in[6];
  const float* g_s = (const float*)d_in[7];
  const float* b_s = (const float*)d_in[8];
  const float* Wih = (const float*)d_in[9];
  const float* Whh = (const float*)d_in[10];
  const float* bih = (const float*)d_in[11];
  const float* bhh = (const float*)d_in[12];
  const float* cb = (const float*)d_in[13];
  float* out = (float*)d_out;

  float* ws = (float*)d_ws;
  float* stats = ws;  ws += 2 * MF;
  float* kbuf = ws;   ws += (size_t)MF * 256;
  float* vbuf = ws;   ws += (size_t)MF * 256;
  float* attn = ws;   ws += (size_t)BATCH * NH * NSLOT * NFEAT;
  float* qbuf = ws;   ws += (size_t)MS * 256;
  float* sbufA = ws;  ws += (size_t)MS * 256;
  float* sbufB = ws;  ws += (size_t)MS * 256;
  float* updb = ws;   ws += (size_t)MS * 256;
  float* updp = ws;   ws += (size_t)512 * NSLOT * 64;
  float* ssump = ws;  ws += (size_t)512 * NSLOT;
  float* Wgk = ws;    ws += 256 * FDIM;
  float* Wgv = ws;    ws += 256 * FDIM;
  float* Wgq = ws;    ws += 256 * 256;
  float* cconst = ws; ws += 768;
  float* bestd2 = ws; ws += MS;

  float* out_slots = out;
  float* out_post = out + 196608;
  float* out_pre = out + 196608 + 786432;
  float* out_idx = out + 196608 + 786432 * 2;
  float* out_commit = out_idx + 768;

  hipMemcpyAsync(sbufA, cond, (size_t)MS * 256 * sizeof(float),
                 hipMemcpyDeviceToDevice, stream);

  k_prep<<<768, 256, 0, stream>>>(Wk, Wv, Wq, g_in, b_in, g_s, b_s, Wgk, Wgv, Wgq, cconst);
  k_rowstats<<<MF / 4, 256, 0, stream>>>(features, stats);
  k_lnkv<<<dim3(MF / 128, 4), 256, 0, stream>>>(features, stats, Wgk, Wgv, cconst, kbuf, vbuf);

  float* scur = sbufA;
  float* snxt = sbufB;
  for (int call = 0; call < 2; ++call) {
    for (int it = 0; it < NITER; ++it) {
      k_lnq<<<dim3(MS / 64, 4), 256, 0, stream>>>(scur, Wgq, cconst, qbuf);
      if (it == NITER - 1)
        k_fdots<true><<<512, 256, 0, stream>>>(qbuf, kbuf, vbuf, attn, updp, ssump);
      else
        k_fdots<false><<<512, 256, 0, stream>>>(qbuf, kbuf, vbuf, attn, updp, ssump);
      k_updfin<<<768, 256, 0, stream>>>(updp, ssump, updb);
      k_grucat<<<dim3(MS / 8, 4), 256, 0, stream>>>(updb, scur, Wih, Whh, bih, bhh, snxt);
      float* tmp = scur; scur = snxt; snxt = tmp;
    }
    k_attnvis<<<BATCH * NSLOT * NFEAT / 256, 256, 0, stream>>>(attn, call ? out_post : out_pre);
    if (call == 0) {
      k_vq<<<MS, 256, 0, stream>>>(scur, cb, out_idx, bestd2);
      k_commit<<<1, 256, 0, stream>>>(bestd2, out_commit);
    }
  }
  k_copy<<<MS, 256, 0, stream>>>(scur, out_slots);
}

// Round 4
// 799.625 us; speedup vs baseline: 8.4072x; 1.3887x over previous
//
#include <hip/hip_runtime.h>
#include <math.h>

#define LB __launch_bounds__(256)

constexpr int BATCH = 32, NFEAT = 1024, FDIM = 768, NSLOT = 24;
constexpr int NH = 4, DH = 64, NITER = 3;
constexpr int MF = BATCH * NFEAT;   // 32768 feature rows
constexpr int MS = BATCH * NSLOT;   // 768 slot rows
constexpr float QSCALE = 0.125f;    // dh^-0.5
constexpr float ATTN_EPS = 1e-8f;
constexpr float LNEPS = 1e-5f;

typedef __attribute__((ext_vector_type(8))) short bf16x8;
typedef __attribute__((ext_vector_type(4))) float f32x4;

// RNE f32 -> bf16 (finite inputs only)
__device__ __forceinline__ unsigned short f2bf(float x) {
  unsigned u = __float_as_uint(x);
  return (unsigned short)((u + 0x7FFFu + ((u >> 16) & 1u)) >> 16);
}
__device__ __forceinline__ float bf2f(unsigned short h) {
  return __uint_as_float(((unsigned)h) << 16);
}

// split 8 f32 (after LN) into hi/lo bf16 packed as int4
__device__ __forceinline__ void cvt8(const float4& a, const float4& b, float m, float r,
                                     int4& hi, int4& lo) {
  float v[8] = {a.x, a.y, a.z, a.w, b.x, b.y, b.z, b.w};
  unsigned sh[8], sl[8];
#pragma unroll
  for (int j = 0; j < 8; ++j) {
    float vv = (v[j] - m) * r;
    unsigned short h = f2bf(vv);
    sh[j] = h;
    sl[j] = f2bf(vv - bf2f(h));
  }
  hi = make_int4((int)(sh[0] | (sh[1] << 16)), (int)(sh[2] | (sh[3] << 16)),
                 (int)(sh[4] | (sh[5] << 16)), (int)(sh[6] | (sh[7] << 16)));
  lo = make_int4((int)(sl[0] | (sl[1] << 16)), (int)(sl[2] | (sl[3] << 16)),
                 (int)(sl[4] | (sl[5] << 16)), (int)(sl[6] | (sl[7] << 16)));
}

// ---- prep: Wk/Wv -> gamma-folded bf16 hi/lo; Wq -> f32 Wgq; cconst[c]=sum_k beta*W ----
__global__ LB void k_prep(const float* __restrict__ Wk, const float* __restrict__ Wv,
                          const float* __restrict__ Wq,
                          const float* __restrict__ g_in, const float* __restrict__ b_in,
                          const float* __restrict__ g_s, const float* __restrict__ b_s,
                          short* __restrict__ Bh_g, short* __restrict__ Bl_g,
                          float* __restrict__ Wgq, float* __restrict__ cconst) {
  const int r = blockIdx.x;
  const int t = threadIdx.x;
  float s = 0.f;
  if (r < 512) {
    const float* srcW = (r < 256) ? (Wk + (size_t)r * FDIM) : (Wv + (size_t)(r - 256) * FDIM);
    for (int k = t; k < FDIM; k += 256) {
      float w = srcW[k];
      float wg = w * g_in[k];
      s += b_in[k] * w;
      unsigned short h = f2bf(wg);
      Bh_g[(size_t)r * FDIM + k] = (short)h;
      Bl_g[(size_t)r * FDIM + k] = (short)f2bf(wg - bf2f(h));
    }
  } else {
    const int c = r - 512;
    const float* srcW = Wq + (size_t)c * 256;
    for (int k = t; k < 256; k += 256) {
      float w = srcW[k];
      Wgq[(size_t)c * 256 + k] = w * g_s[k];
      s += b_s[k] * w;
    }
  }
  __shared__ float red[256];
  red[t] = s; __syncthreads();
  for (int o = 128; o > 0; o >>= 1) { if (t < o) red[t] += red[t + o]; __syncthreads(); }
  if (t == 0) cconst[r] = red[0];
}

// ---------------- per-row mean/rstd of features ----------------
__global__ LB void k_rowstats(const float* __restrict__ x, float* __restrict__ stats) {
  const int row = blockIdx.x * 4 + (threadIdx.x >> 6);
  const int lane = threadIdx.x & 63;
  const float* xr = x + (size_t)row * FDIM;
  float s = 0.f, sq = 0.f;
#pragma unroll
  for (int i = 0; i < 3; ++i) {
    float4 v = *(const float4*)(xr + i * 256 + lane * 4);
    s += v.x + v.y + v.z + v.w;
    sq += v.x * v.x + v.y * v.y + v.z * v.z + v.w * v.w;
  }
#pragma unroll
  for (int o = 32; o > 0; o >>= 1) { s += __shfl_down(s, o, 64); sq += __shfl_down(sq, o, 64); }
  if (lane == 0) {
    float m = s / (float)FDIM;
    float var = sq / (float)FDIM - m * m;
    stats[row * 2] = m;
    stats[row * 2 + 1] = 1.f / sqrtf(var + LNEPS);
  }
}

// -------- MFMA split-bf16: LN(features) @ Wg^T -> k,v (f32 out) --------
// 128x128 tile, BK=32, 4 waves (2x2 of 64x64), 16x16x32 bf16 MFMA, 3-product split.
// LDS 16B-granule XOR swizzle: slot(row,kq) = row*4 + (kq ^ ((row>>1)&3)) -> 2-way max.
__global__ LB void k_mfkv(const float* __restrict__ x, const float* __restrict__ stats,
                          const short* __restrict__ Bh_g, const short* __restrict__ Bl_g,
                          const float* __restrict__ cconst,
                          float* __restrict__ kout, float* __restrict__ vout) {
  __shared__ short Ah[4096], Al[4096], Bh[4096], Bl[4096];  // each [128][32] bf16, 8KB
  const int t = threadIdx.x;
  const int l = t & 63;
  const int w = t >> 6;
  const int row0 = blockIdx.x * 128;
  const int ncol0 = blockIdx.y * 128;          // global col in [k(0..255) | v(256..511)]
  float* Cout = (ncol0 < 256) ? kout : vout;
  const int wc0 = ncol0 & 255;                 // 0 or 128 within its buffer
  const int coff = (ncol0 < 256) ? 0 : 256;

  // staging: thread owns LDS slots S0=t, S1=t+256 per buffer (slot = 16B)
  const int s_row0 = t >> 2;
  const int s_sl = t & 3;
  const int s_kq0 = s_sl ^ ((s_row0 >> 1) & 3);
  const int s_row1 = s_row0 + 64;
  const int s_kq1 = s_sl ^ ((s_row1 >> 1) & 3);
  const float* pa0 = x + (size_t)(row0 + s_row0) * FDIM + s_kq0 * 8;
  const float* pa1 = x + (size_t)(row0 + s_row1) * FDIM + s_kq1 * 8;
  const float m0 = stats[(row0 + s_row0) * 2], r0 = stats[(row0 + s_row0) * 2 + 1];
  const float m1 = stats[(row0 + s_row1) * 2], r1 = stats[(row0 + s_row1) * 2 + 1];
  const short* pbh0 = Bh_g + (size_t)(ncol0 + s_row0) * FDIM + s_kq0 * 8;
  const short* pbh1 = Bh_g + (size_t)(ncol0 + s_row1) * FDIM + s_kq1 * 8;
  const short* pbl0 = Bl_g + (size_t)(ncol0 + s_row0) * FDIM + s_kq0 * 8;
  const short* pbl1 = Bl_g + (size_t)(ncol0 + s_row1) * FDIM + s_kq1 * 8;
  const int wb0 = t * 16, wb1 = (t + 256) * 16;

  // fragment read byte offsets (same swizzle)
  const int wm = (w >> 1) * 64, wn = (w & 1) * 64;
  int aoff[4], boff[4];
#pragma unroll
  for (int m = 0; m < 4; ++m) {
    const int ar = wm + m * 16 + (l & 15);
    const int kq = l >> 4;
    aoff[m] = ar * 64 + ((kq ^ ((ar >> 1) & 3)) << 4);
    const int bc = wn + m * 16 + (l & 15);
    boff[m] = bc * 64 + ((kq ^ ((bc >> 1) & 3)) << 4);
  }

  f32x4 acc[4][4] = {};
  float4 ra0a = *(const float4*)pa0, ra0b = *(const float4*)(pa0 + 4);
  float4 ra1a = *(const float4*)pa1, ra1b = *(const float4*)(pa1 + 4);
  int4 rbh0 = *(const int4*)pbh0, rbh1 = *(const int4*)pbh1;
  int4 rbl0 = *(const int4*)pbl0, rbl1 = *(const int4*)pbl1;

  for (int s = 0; s < FDIM / 32; ++s) {
    if (s) __syncthreads();
    int4 hi, lo;
    cvt8(ra0a, ra0b, m0, r0, hi, lo);
    *(int4*)((char*)Ah + wb0) = hi; *(int4*)((char*)Al + wb0) = lo;
    cvt8(ra1a, ra1b, m1, r1, hi, lo);
    *(int4*)((char*)Ah + wb1) = hi; *(int4*)((char*)Al + wb1) = lo;
    *(int4*)((char*)Bh + wb0) = rbh0; *(int4*)((char*)Bh + wb1) = rbh1;
    *(int4*)((char*)Bl + wb0) = rbl0; *(int4*)((char*)Bl + wb1) = rbl1;
    if (s + 1 < FDIM / 32) {
      const int ko = (s + 1) * 32;
      ra0a = *(const float4*)(pa0 + ko); ra0b = *(const float4*)(pa0 + ko + 4);
      ra1a = *(const float4*)(pa1 + ko); ra1b = *(const float4*)(pa1 + ko + 4);
      rbh0 = *(const int4*)(pbh0 + ko); rbh1 = *(const int4*)(pbh1 + ko);
      rbl0 = *(const int4*)(pbl0 + ko); rbl1 = *(const int4*)(pbl1 + ko);
    }
    __syncthreads();
    bf16x8 fah[4], fal[4], fbh[4], fbl[4];
#pragma unroll
    for (int m = 0; m < 4; ++m) {
      fah[m] = *(const bf16x8*)((const char*)Ah + aoff[m]);
      fal[m] = *(const bf16x8*)((const char*)Al + aoff[m]);
      fbh[m] = *(const bf16x8*)((const char*)Bh + boff[m]);
      fbl[m] = *(const bf16x8*)((const char*)Bl + boff[m]);
    }
#pragma unroll
    for (int m = 0; m < 4; ++m)
#pragma unroll
      for (int n = 0; n < 4; ++n) {
        acc[m][n] = __builtin_amdgcn_mfma_f32_16x16x32_bf16(fal[m], fbh[n], acc[m][n], 0, 0, 0);
        acc[m][n] = __builtin_amdgcn_mfma_f32_16x16x32_bf16(fah[m], fbl[n], acc[m][n], 0, 0, 0);
        acc[m][n] = __builtin_amdgcn_mfma_f32_16x16x32_bf16(fah[m], fbh[n], acc[m][n], 0, 0, 0);
      }
  }
  // epilogue: D mapping col=lane&15, row=(lane>>4)*4+reg (m89-verified)
#pragma unroll
  for (int m = 0; m < 4; ++m) {
    const int rbase = row0 + wm + m * 16 + ((l >> 4) << 2);
#pragma unroll
    for (int n = 0; n < 4; ++n) {
      const int col = wc0 + wn + n * 16 + (l & 15);
      const float cc = cconst[coff + col];
#pragma unroll
      for (int r = 0; r < 4; ++r)
        Cout[(size_t)(rbase + r) * 256 + col] = acc[m][n][r] + cc;
    }
  }
}

// ---- fused: LN(slots)+q -> dots -> softmax -> partial sums + partial V-mix ----
// grid (b,h,jc) = 512 blocks; q computed redundantly per jc (deterministic).
template <bool WRITE_ATTN>
__global__ LB void k_fdots(const float* __restrict__ slots, const float* __restrict__ Wgq,
                           const float* __restrict__ cconst,
                           const float* __restrict__ kmat, const float* __restrict__ vmat,
                           float* __restrict__ attn, float* __restrict__ updp,
                           float* __restrict__ ssump) {
  const int blk = blockIdx.x;
  const int jc = blk & 3;
  const int h = (blk >> 2) & 3;
  const int b = blk >> 4;
  const int t = threadIdx.x;
  __shared__ float U[NSLOT][256];     // sn, then reused as at
  __shared__ float qs[NSLOT][DH];
  __shared__ float vt[DH][DH];
  __shared__ float ssr[NSLOT][8];
  __shared__ float mst[NSLOT], rst[NSLOT];
  // LN stats + stash slots rows in U
  if (t < 192) {
    const int r = t >> 3, g = t & 7;
    const float* sr = slots + (size_t)(b * NSLOT + r) * 256 + g * 32;
    float s = 0.f, sq = 0.f;
#pragma unroll
    for (int m4 = 0; m4 < 8; ++m4) {
      float4 v = *(const float4*)(sr + m4 * 4);
      *(float4*)&U[r][g * 32 + m4 * 4] = v;
      s += v.x + v.y + v.z + v.w;
      sq += v.x * v.x + v.y * v.y + v.z * v.z + v.w * v.w;
    }
    s += __shfl_down(s, 4, 8); sq += __shfl_down(sq, 4, 8);
    s += __shfl_down(s, 2, 8); sq += __shfl_down(sq, 2, 8);
    s += __shfl_down(s, 1, 8); sq += __shfl_down(sq, 1, 8);
    if (g == 0) {
      float mm = s * (1.f / 256.f);
      mst[r] = mm;
      rst[r] = 1.f / sqrtf(sq * (1.f / 256.f) - mm * mm + LNEPS);
    }
  }
  __syncthreads();
  for (int lidx = t; lidx < NSLOT * 256; lidx += 256) {
    const int i = lidx >> 8, kk = lidx & 255;
    U[i][kk] = (U[i][kk] - mst[i]) * rst[i];
  }
  __syncthreads();
  // q[i][d] = U[i][:] . Wgq[h*64+d][:] + cconst[512+h*64+d]
  {
    const int d = t & 63, ig = t >> 6;
    const float* wrow = Wgq + (size_t)(h * 64 + d) * 256;
    float aq[6] = {};
    for (int k4 = 0; k4 < 256; k4 += 4) {
      const float4 wv = *(const float4*)(wrow + k4);
#pragma unroll
      for (int u = 0; u < 6; ++u) {
        const float4 uv = *(const float4*)&U[ig * 6 + u][k4];
        aq[u] += uv.x * wv.x + uv.y * wv.y + uv.z * wv.z + uv.w * wv.w;
      }
    }
    const float qc = cconst[512 + h * 64 + d];
#pragma unroll
    for (int u = 0; u < 6; ++u) qs[ig * 6 + u][d] = aq[u] + qc;
  }
  __syncthreads();
  // dots + softmax over slots
  const int j = jc * 256 + t;
  const float* kr = kmat + (size_t)(b * NFEAT + j) * 256 + h * 64;
  float acc[NSLOT] = {};
#pragma unroll
  for (int d4 = 0; d4 < DH; d4 += 4) {
    float4 kv = *(const float4*)(kr + d4);
#pragma unroll
    for (int i = 0; i < NSLOT; ++i) {
      float4 qv = *(const float4*)&qs[i][d4];
      acc[i] += qv.x * kv.x + qv.y * kv.y + qv.z * kv.z + qv.w * kv.w;
    }
  }
  float mx = -1e30f;
#pragma unroll
  for (int i = 0; i < NSLOT; ++i) { acc[i] *= QSCALE; mx = fmaxf(mx, acc[i]); }
  float s = 0.f;
#pragma unroll
  for (int i = 0; i < NSLOT; ++i) { acc[i] = expf(acc[i] - mx); s += acc[i]; }
  const float inv = 1.f / s;
  float* ab = attn + (size_t)(b * NH + h) * NSLOT * NFEAT + j;
#pragma unroll
  for (int i = 0; i < NSLOT; ++i) {
    const float wgt = acc[i] * inv;
    if (WRITE_ATTN) ab[(size_t)i * NFEAT] = wgt;
    U[i][t] = wgt + ATTN_EPS;
  }
  __syncthreads();
  // partial row sums of (attn+eps), rotated to dodge conflicts
  if (t < 192) {
    const int i = t >> 3, s8 = t & 7;
    float sp = 0.f;
#pragma unroll
    for (int m = 0; m < 32; ++m) sp += U[i][s8 * 32 + ((m + t) & 31)];
    ssr[i][s8] = sp;
  }
  // partial V mix
  const int d = t & 63;
  const int ig = t >> 6;
  float acc2[6] = {};
  for (int j0 = 0; j0 < 256; j0 += 64) {
    __syncthreads();
#pragma unroll
    for (int rl = 0; rl < 4; ++rl) {
      const int lidx = rl * 1024 + t * 4;
      const int jj = lidx >> 6, dd = lidx & 63;
      *(float4*)&vt[jj][dd] =
          *(const float4*)(vmat + (size_t)(b * NFEAT + jc * 256 + j0 + jj) * 256 + h * 64 + dd);
    }
    __syncthreads();
#pragma unroll 16
    for (int jj = 0; jj < 64; ++jj) {
      const float vv = vt[jj][d];
#pragma unroll
      for (int u = 0; u < 6; ++u) acc2[u] += U[ig * 6 + u][j0 + jj] * vv;
    }
  }
  __syncthreads();
  if (t < NSLOT) {
    float sp = 0.f;
#pragma unroll
    for (int u = 0; u < 8; ++u) sp += ssr[t][u];
    ssump[((size_t)(b * NH + h) * 4 + jc) * NSLOT + t] = sp;
  }
  float* up = updp + (((size_t)(b * NH + h) * 4 + jc) * NSLOT) * 64;
#pragma unroll
  for (int u = 0; u < 6; ++u) up[(ig * 6 + u) * 64 + d] = acc2[u];
}

// ---- finalize: upd = (sum_jc updp) / (sum_jc ssump), layout [b][i][h][d] ----
__global__ LB void k_updfin(const float* __restrict__ updp, const float* __restrict__ ssump,
                            float* __restrict__ upd) {
  const int gid = blockIdx.x * 256 + threadIdx.x;
  const int d = gid & 63;
  const int h = (gid >> 6) & 3;
  const int rem = gid >> 8;
  const int i = rem % 24;
  const int b = rem / 24;
  float s = 0.f, w = 0.f;
#pragma unroll
  for (int jc = 0; jc < 4; ++jc) {
    const size_t base = (size_t)(b * NH + h) * 4 + jc;
    s += updp[base * NSLOT * 64 + i * 64 + d];
    w += ssump[base * NSLOT + i];
  }
  upd[gid] = s / w;
}

// ---- fused GRU: 8-row x 64-dim tiles (384 blocks), both GEMMs + elementwise ----
__global__ LB void k_grucat(const float* __restrict__ upd, const float* __restrict__ sprev,
                            const float* __restrict__ Wih, const float* __restrict__ Whh,
                            const float* __restrict__ bih, const float* __restrict__ bhh,
                            float* __restrict__ snext) {
  __shared__ float As[16][8];
  __shared__ float Bs[3][16][66];
  const int row0 = blockIdx.x * 8;
  const int d0 = blockIdx.y * 64;
  const int t = threadIdx.x;
  const int r = t >> 5;
  const int dd = (t & 31) * 2;
  const int bc = t >> 2;
  const int bk4 = (t & 3) * 4;
  float accR[2] = {}, accZ[2] = {}, accN[2] = {}, accH[2] = {};
  for (int k0 = 0; k0 < 256; k0 += 16) {
    if (t < 128) As[t & 15][t >> 4] = upd[(size_t)(row0 + (t >> 4)) * 256 + k0 + (t & 15)];
#pragma unroll
    for (int s = 0; s < 3; ++s) {
      float4 w = *(const float4*)(Wih + (size_t)(s * 256 + d0 + bc) * 256 + k0 + bk4);
      Bs[s][bk4 + 0][bc] = w.x; Bs[s][bk4 + 1][bc] = w.y;
      Bs[s][bk4 + 2][bc] = w.z; Bs[s][bk4 + 3][bc] = w.w;
    }
    __syncthreads();
#pragma unroll
    for (int kk = 0; kk < 16; ++kk) {
      const float a = As[kk][r];
      const float2 b0 = *(const float2*)&Bs[0][kk][dd];
      const float2 b1 = *(const float2*)&Bs[1][kk][dd];
      const float2 b2 = *(const float2*)&Bs[2][kk][dd];
      accR[0] += a * b0.x; accR[1] += a * b0.y;
      accZ[0] += a * b1.x; accZ[1] += a * b1.y;
      accN[0] += a * b2.x; accN[1] += a * b2.y;
    }
    __syncthreads();
  }
  for (int k0 = 0; k0 < 256; k0 += 16) {
    if (t < 128) As[t & 15][t >> 4] = sprev[(size_t)(row0 + (t >> 4)) * 256 + k0 + (t & 15)];
#pragma unroll
    for (int s = 0; s < 3; ++s) {
      float4 w = *(const float4*)(Whh + (size_t)(s * 256 + d0 + bc) * 256 + k0 + bk4);
      Bs[s][bk4 + 0][bc] = w.x; Bs[s][bk4 + 1][bc] = w.y;
      Bs[s][bk4 + 2][bc] = w.z; Bs[s][bk4 + 3][bc] = w.w;
    }
    __syncthreads();
#pragma unroll
    for (int kk = 0; kk < 16; ++kk) {
      const float a = As[kk][r];
      const float2 b0 = *(const float2*)&Bs[0][kk][dd];
      const float2 b1 = *(const float2*)&Bs[1][kk][dd];
      const float2 b2 = *(const float2*)&Bs[2][kk][dd];
      accR[0] += a * b0.x; accR[1] += a * b0.y;
      accZ[0] += a * b1.x; accZ[1] += a * b1.y;
      accH[0] += a * b2.x; accH[1] += a * b2.y;
    }
    __syncthreads();
  }
  const int row = row0 + r;
  const float2 hp = *(const float2*)(sprev + (size_t)row * 256 + d0 + dd);
  const float hpv[2] = {hp.x, hp.y};
  float o[2];
#pragma unroll
  for (int x = 0; x < 2; ++x) {
    const int c = d0 + dd + x;
    const float rr = 1.f / (1.f + expf(-(accR[x] + bih[c] + bhh[c])));
    const float zz = 1.f / (1.f + expf(-(accZ[x] + bih[256 + c] + bhh[256 + c])));
    const float nn = tanhf(accN[x] + bih[512 + c] + rr * (accH[x] + bhh[512 + c]));
    o[x] = (1.f - zz) * nn + zz * hpv[x];
  }
  *(float2*)(snext + (size_t)row * 256 + d0 + dd) = make_float2(o[0], o[1]);
}

// ---------------- attn_vis = mean over heads ----------------
__global__ LB void k_attnvis(const float* __restrict__ attn, float* __restrict__ out) {
  const int idx = blockIdx.x * 256 + threadIdx.x;
  const int j = idx & 1023;
  const int rem = idx >> 10;
  const int i = rem % NSLOT;
  const int b = rem / NSLOT;
  float s = 0.f;
#pragma unroll
  for (int h = 0; h < NH; ++h)
    s += attn[(size_t)((b * NH + h) * NSLOT + i) * NFEAT + j];
  out[idx] = 0.25f * s;
}

// ---- VQ argmin (ref formula) + straight-through in-place ----
__global__ LB void k_vq(float* __restrict__ slots, const float* __restrict__ cb,
                        float* __restrict__ idx_out, float* __restrict__ bestd2) {
  const int r = blockIdx.x;
  const int t = threadIdx.x;
  __shared__ float xs[256];
  __shared__ float red[256];
  __shared__ float rv[256];
  __shared__ int ri[256];
  xs[t] = slots[(size_t)r * 256 + t];
  __syncthreads();
  red[t] = xs[t] * xs[t]; __syncthreads();
  for (int o = 128; o > 0; o >>= 1) { if (t < o) red[t] += red[t + o]; __syncthreads(); }
  const float x2 = red[0];
  float best = 1e30f; int bidx = 0;
#pragma unroll
  for (int cset = 0; cset < 2; ++cset) {
    const int c = cset * 256 + t;
    const float* cr = cb + (size_t)c * 256;
    float xc = 0.f, cc = 0.f;
    for (int dd = 0; dd < 256; dd += 4) {
      float4 cv = *(const float4*)(cr + dd);
      xc += xs[dd] * cv.x + xs[dd + 1] * cv.y + xs[dd + 2] * cv.z + xs[dd + 3] * cv.w;
      cc += cv.x * cv.x + cv.y * cv.y + cv.z * cv.z + cv.w * cv.w;
    }
    float d2 = x2 - 2.f * xc + cc;
    if (d2 < best) { best = d2; bidx = c; }
  }
  rv[t] = best; ri[t] = bidx; __syncthreads();
  for (int o = 128; o > 0; o >>= 1) {
    if (t < o) {
      if (rv[t + o] < rv[t] || (rv[t + o] == rv[t] && ri[t + o] < ri[t])) {
        rv[t] = rv[t + o]; ri[t] = ri[t + o];
      }
    }
    __syncthreads();
  }
  const int wi = ri[0];
  const float cval = cb[(size_t)wi * 256 + t];
  const float diff = xs[t] - cval;
  red[t] = diff * diff; __syncthreads();
  for (int o = 128; o > 0; o >>= 1) { if (t < o) red[t] += red[t + o]; __syncthreads(); }
  if (t == 0) { idx_out[r] = (float)wi; bestd2[r] = red[0]; }
  slots[(size_t)r * 256 + t] = cval;
}

__global__ LB void k_commit(const float* __restrict__ bestd2, float* __restrict__ out) {
  const int t = threadIdx.x;
  __shared__ float red[256];
  float s = 0.f;
  for (int i = t; i < MS; i += 256) s += bestd2[i];
  red[t] = s; __syncthreads();
  for (int o = 128; o > 0; o >>= 1) { if (t < o) red[t] += red[t + o]; __syncthreads(); }
  if (t == 0) out[0] = red[0] / (float)(MS * 256);
}

__global__ LB void k_copy(const float* __restrict__ src, float* __restrict__ dst) {
  const int i = blockIdx.x * 256 + threadIdx.x;
  dst[i] = src[i];
}

extern "C" void kernel_launch(void* const* d_in, const int* in_sizes, int n_in,
                              void* d_out, int out_size, void* d_ws, size_t ws_size,
                              hipStream_t stream) {
  const float* features = (const float*)d_in[0];
  const float* cond = (const float*)d_in[1];
  const float* Wq = (const float*)d_in[2];
  const float* Wk = (const float*)d_in[3];
  const float* Wv = (const float*)d_in[4];
  const float* g_in = (const float*)d_in[5];
  const float* b_in = (const float*)d_in[6];
  const float* g_s = (const float*)d_in[7];
  const float* b_s = (const float*)d_in[8];
  const float* Wih = (const float*)d_in[9];
  const float* Whh = (const float*)d_in[10];
  const float* bih = (const float*)d_in[11];
  const float* bhh = (const float*)d_in[12];
  const float* cb = (const float*)d_in[13];
  float* out = (float*)d_out;

  // short arrays first (16B aligned), then floats
  char* wsb = (char*)d_ws;
  short* Bh_g = (short*)wsb; wsb += (size_t)512 * FDIM * 2;
  short* Bl_g = (short*)wsb; wsb += (size_t)512 * FDIM * 2;
  float* ws = (float*)wsb;
  float* stats = ws;  ws += 2 * MF;
  float* kbuf = ws;   ws += (size_t)MF * 256;
  float* vbuf = ws;   ws += (size_t)MF * 256;
  float* attn = ws;   ws += (size_t)BATCH * NH * NSLOT * NFEAT;
  float* sbufA = ws;  ws += (size_t)MS * 256;
  float* sbufB = ws;  ws += (size_t)MS * 256;
  float* updb = ws;   ws += (size_t)MS * 256;
  float* updp = ws;   ws += (size_t)512 * NSLOT * 64;
  float* ssump = ws;  ws += (size_t)512 * NSLOT;
  float* Wgq = ws;    ws += 256 * 256;
  float* cconst = ws; ws += 768;
  float* bestd2 = ws; ws += MS;

  float* out_slots = out;
  float* out_post = out + 196608;
  float* out_pre = out + 196608 + 786432;
  float* out_idx = out + 196608 + 786432 * 2;
  float* out_commit = out_idx + 768;

  hipMemcpyAsync(sbufA, cond, (size_t)MS * 256 * sizeof(float),
                 hipMemcpyDeviceToDevice, stream);

  k_prep<<<768, 256, 0, stream>>>(Wk, Wv, Wq, g_in, b_in, g_s, b_s, Bh_g, Bl_g, Wgq, cconst);
  k_rowstats<<<MF / 4, 256, 0, stream>>>(features, stats);
  k_mfkv<<<dim3(MF / 128, 4), 256, 0, stream>>>(features, stats, Bh_g, Bl_g, cconst, kbuf, vbuf);

  float* scur = sbufA;
  float* snxt = sbufB;
  for (int call = 0; call < 2; ++call) {
    for (int it = 0; it < NITER; ++it) {
      if (it == NITER - 1)
        k_fdots<true><<<512, 256, 0, stream>>>(scur, Wgq, cconst, kbuf, vbuf, attn, updp, ssump);
      else
        k_fdots<false><<<512, 256, 0, stream>>>(scur, Wgq, cconst, kbuf, vbuf, attn, updp, ssump);
      k_updfin<<<768, 256, 0, stream>>>(updp, ssump, updb);
      k_grucat<<<dim3(MS / 8, 4), 256, 0, stream>>>(updb, scur, Wih, Whh, bih, bhh, snxt);
      float* tmp = scur; scur = snxt; snxt = tmp;
    }
    k_attnvis<<<BATCH * NSLOT * NFEAT / 256, 256, 0, stream>>>(attn, call ? out_post : out_pre);
    if (call == 0) {
      k_vq<<<MS, 256, 0, stream>>>(scur, cb, out_idx, bestd2);
      k_commit<<<1, 256, 0, stream>>>(bestd2, out_commit);
    }
  }
  k_copy<<<MS, 256, 0, stream>>>(scur, out_slots);
}

// Round 7
// 717.409 us; speedup vs baseline: 9.3707x; 1.1146x over previous
//
#include <hip/hip_runtime.h>
#include <math.h>

#define LB __launch_bounds__(256)

constexpr int BATCH = 32, NFEAT = 1024, FDIM = 768, NSLOT = 24;
constexpr int NH = 4, DH = 64, NITER = 3;
constexpr int MF = BATCH * NFEAT;   // 32768 feature rows
constexpr int MS = BATCH * NSLOT;   // 768 slot rows
constexpr float QSCALE = 0.125f;    // dh^-0.5
constexpr float ATTN_EPS = 1e-8f;
constexpr float LNEPS = 1e-5f;

typedef __attribute__((ext_vector_type(8))) short bf16x8;
typedef __attribute__((ext_vector_type(4))) float f32x4;

__device__ __forceinline__ unsigned short f2bf(float x) {
  unsigned u = __float_as_uint(x);
  return (unsigned short)((u + 0x7FFFu + ((u >> 16) & 1u)) >> 16);
}
__device__ __forceinline__ float bf2f(unsigned short h) {
  return __uint_as_float(((unsigned)h) << 16);
}
__device__ __forceinline__ void cvt8(const float4& a, const float4& b, float m, float r,
                                     int4& hi, int4& lo) {
  float v[8] = {a.x, a.y, a.z, a.w, b.x, b.y, b.z, b.w};
  unsigned sh[8], sl[8];
#pragma unroll
  for (int j = 0; j < 8; ++j) {
    float vv = (v[j] - m) * r;
    unsigned short h = f2bf(vv);
    sh[j] = h;
    sl[j] = f2bf(vv - bf2f(h));
  }
  hi = make_int4((int)(sh[0] | (sh[1] << 16)), (int)(sh[2] | (sh[3] << 16)),
                 (int)(sh[4] | (sh[5] << 16)), (int)(sh[6] | (sh[7] << 16)));
  lo = make_int4((int)(sl[0] | (sl[1] << 16)), (int)(sl[2] | (sl[3] << 16)),
                 (int)(sl[4] | (sl[5] << 16)), (int)(sl[6] | (sl[7] << 16)));
}

// ---- merged: blocks [0,8192) rowstats; [8192,8960) weight prep ----
__global__ LB void k_preprow(const float* __restrict__ x, float* __restrict__ stats,
                             const float* __restrict__ Wk, const float* __restrict__ Wv,
                             const float* __restrict__ Wq,
                             const float* __restrict__ g_in, const float* __restrict__ b_in,
                             const float* __restrict__ g_s, const float* __restrict__ b_s,
                             short* __restrict__ Bh_g, short* __restrict__ Bl_g,
                             float* __restrict__ Wgq, float* __restrict__ cconst) {
  const int t = threadIdx.x;
  if (blockIdx.x < MF / 4) {
    const int row = blockIdx.x * 4 + (t >> 6);
    const int lane = t & 63;
    const float* xr = x + (size_t)row * FDIM;
    float s = 0.f, sq = 0.f;
#pragma unroll
    for (int i = 0; i < 3; ++i) {
      float4 v = *(const float4*)(xr + i * 256 + lane * 4);
      s += v.x + v.y + v.z + v.w;
      sq += v.x * v.x + v.y * v.y + v.z * v.z + v.w * v.w;
    }
#pragma unroll
    for (int o = 32; o > 0; o >>= 1) { s += __shfl_down(s, o, 64); sq += __shfl_down(sq, o, 64); }
    if (lane == 0) {
      float m = s / (float)FDIM;
      float var = sq / (float)FDIM - m * m;
      stats[row * 2] = m;
      stats[row * 2 + 1] = 1.f / sqrtf(var + LNEPS);
    }
    return;
  }
  const int r = blockIdx.x - MF / 4;
  float s = 0.f;
  if (r < 512) {
    const float* srcW = (r < 256) ? (Wk + (size_t)r * FDIM) : (Wv + (size_t)(r - 256) * FDIM);
    for (int k = t; k < FDIM; k += 256) {
      float w = srcW[k];
      float wg = w * g_in[k];
      s += b_in[k] * w;
      unsigned short h = f2bf(wg);
      Bh_g[(size_t)r * FDIM + k] = (short)h;
      Bl_g[(size_t)r * FDIM + k] = (short)f2bf(wg - bf2f(h));
    }
  } else {
    const int c = r - 512;
    float w = Wq[(size_t)c * 256 + t];
    Wgq[(size_t)c * 256 + t] = w * g_s[t];
    s = b_s[t] * w;
  }
  __shared__ float red[256];
  red[t] = s; __syncthreads();
  for (int o = 128; o > 0; o >>= 1) { if (t < o) red[t] += red[t + o]; __syncthreads(); }
  if (t == 0) cconst[r] = red[0];
}

// -------- MFMA split-bf16: LN(features) @ Wg^T -> k,v (round-4 proven) --------
__global__ LB void k_mfkv(const float* __restrict__ x, const float* __restrict__ stats,
                          const short* __restrict__ Bh_g, const short* __restrict__ Bl_g,
                          const float* __restrict__ cconst,
                          float* __restrict__ kout, float* __restrict__ vout) {
  __shared__ short Ah[4096], Al[4096], Bh[4096], Bl[4096];
  const int t = threadIdx.x;
  const int l = t & 63;
  const int w = t >> 6;
  const int row0 = blockIdx.x * 128;
  const int ncol0 = blockIdx.y * 128;
  float* Cout = (ncol0 < 256) ? kout : vout;
  const int wc0 = ncol0 & 255;
  const int coff = (ncol0 < 256) ? 0 : 256;

  const int s_row0 = t >> 2;
  const int s_sl = t & 3;
  const int s_kq0 = s_sl ^ ((s_row0 >> 1) & 3);
  const int s_row1 = s_row0 + 64;
  const int s_kq1 = s_sl ^ ((s_row1 >> 1) & 3);
  const float* pa0 = x + (size_t)(row0 + s_row0) * FDIM + s_kq0 * 8;
  const float* pa1 = x + (size_t)(row0 + s_row1) * FDIM + s_kq1 * 8;
  const float m0 = stats[(row0 + s_row0) * 2], r0 = stats[(row0 + s_row0) * 2 + 1];
  const float m1 = stats[(row0 + s_row1) * 2], r1 = stats[(row0 + s_row1) * 2 + 1];
  const short* pbh0 = Bh_g + (size_t)(ncol0 + s_row0) * FDIM + s_kq0 * 8;
  const short* pbh1 = Bh_g + (size_t)(ncol0 + s_row1) * FDIM + s_kq1 * 8;
  const short* pbl0 = Bl_g + (size_t)(ncol0 + s_row0) * FDIM + s_kq0 * 8;
  const short* pbl1 = Bl_g + (size_t)(ncol0 + s_row1) * FDIM + s_kq1 * 8;
  const int wb0 = t * 16, wb1 = (t + 256) * 16;

  const int wm = (w >> 1) * 64, wn = (w & 1) * 64;
  int aoff[4], boff[4];
#pragma unroll
  for (int m = 0; m < 4; ++m) {
    const int ar = wm + m * 16 + (l & 15);
    const int kq = l >> 4;
    aoff[m] = ar * 64 + ((kq ^ ((ar >> 1) & 3)) << 4);
    const int bc = wn + m * 16 + (l & 15);
    boff[m] = bc * 64 + ((kq ^ ((bc >> 1) & 3)) << 4);
  }

  f32x4 acc[4][4] = {};
  float4 ra0a = *(const float4*)pa0, ra0b = *(const float4*)(pa0 + 4);
  float4 ra1a = *(const float4*)pa1, ra1b = *(const float4*)(pa1 + 4);
  int4 rbh0 = *(const int4*)pbh0, rbh1 = *(const int4*)pbh1;
  int4 rbl0 = *(const int4*)pbl0, rbl1 = *(const int4*)pbl1;

  for (int s = 0; s < FDIM / 32; ++s) {
    if (s) __syncthreads();
    int4 hi, lo;
    cvt8(ra0a, ra0b, m0, r0, hi, lo);
    *(int4*)((char*)Ah + wb0) = hi; *(int4*)((char*)Al + wb0) = lo;
    cvt8(ra1a, ra1b, m1, r1, hi, lo);
    *(int4*)((char*)Ah + wb1) = hi; *(int4*)((char*)Al + wb1) = lo;
    *(int4*)((char*)Bh + wb0) = rbh0; *(int4*)((char*)Bh + wb1) = rbh1;
    *(int4*)((char*)Bl + wb0) = rbl0; *(int4*)((char*)Bl + wb1) = rbl1;
    if (s + 1 < FDIM / 32) {
      const int ko = (s + 1) * 32;
      ra0a = *(const float4*)(pa0 + ko); ra0b = *(const float4*)(pa0 + ko + 4);
      ra1a = *(const float4*)(pa1 + ko); ra1b = *(const float4*)(pa1 + ko + 4);
      rbh0 = *(const int4*)(pbh0 + ko); rbh1 = *(const int4*)(pbh1 + ko);
      rbl0 = *(const int4*)(pbl0 + ko); rbl1 = *(const int4*)(pbl1 + ko);
    }
    __syncthreads();
    bf16x8 fah[4], fal[4], fbh[4], fbl[4];
#pragma unroll
    for (int m = 0; m < 4; ++m) {
      fah[m] = *(const bf16x8*)((const char*)Ah + aoff[m]);
      fal[m] = *(const bf16x8*)((const char*)Al + aoff[m]);
      fbh[m] = *(const bf16x8*)((const char*)Bh + boff[m]);
      fbl[m] = *(const bf16x8*)((const char*)Bl + boff[m]);
    }
#pragma unroll
    for (int m = 0; m < 4; ++m)
#pragma unroll
      for (int n = 0; n < 4; ++n) {
        acc[m][n] = __builtin_amdgcn_mfma_f32_16x16x32_bf16(fal[m], fbh[n], acc[m][n], 0, 0, 0);
        acc[m][n] = __builtin_amdgcn_mfma_f32_16x16x32_bf16(fah[m], fbl[n], acc[m][n], 0, 0, 0);
        acc[m][n] = __builtin_amdgcn_mfma_f32_16x16x32_bf16(fah[m], fbh[n], acc[m][n], 0, 0, 0);
      }
  }
#pragma unroll
  for (int m = 0; m < 4; ++m) {
    const int rbase = row0 + wm + m * 16 + ((l >> 4) << 2);
#pragma unroll
    for (int n = 0; n < 4; ++n) {
      const int col = wc0 + wn + n * 16 + (l & 15);
      const float cc = cconst[coff + col];
#pragma unroll
      for (int r = 0; r < 4; ++r)
        Cout[(size_t)(rbase + r) * 256 + col] = acc[m][n][r] + cc;
    }
  }
}

// ---- fused: LN(slots)+q -> dots -> softmax -> partial sums + partial V-mix ----
template <bool WRITE_ATTN>
__global__ LB void k_fdots(const float* __restrict__ slots, const float* __restrict__ Wgq,
                           const float* __restrict__ cconst,
                           const float* __restrict__ kmat, const float* __restrict__ vmat,
                           float* __restrict__ attn, float* __restrict__ updp,
                           float* __restrict__ ssump) {
  const int blk = blockIdx.x;
  const int jc = blk & 3;
  const int h = (blk >> 2) & 3;
  const int b = blk >> 4;
  const int t = threadIdx.x;
  __shared__ float U[NSLOT][256];
  __shared__ float qs[NSLOT][DH];
  __shared__ float vt[DH][DH];
  __shared__ float ssr[NSLOT][8];
  __shared__ float mst[NSLOT], rst[NSLOT];
  if (t < 192) {
    const int r = t >> 3, g = t & 7;
    const float* sr = slots + (size_t)(b * NSLOT + r) * 256 + g * 32;
    float s = 0.f, sq = 0.f;
#pragma unroll
    for (int m4 = 0; m4 < 8; ++m4) {
      float4 v = *(const float4*)(sr + m4 * 4);
      *(float4*)&U[r][g * 32 + m4 * 4] = v;
      s += v.x + v.y + v.z + v.w;
      sq += v.x * v.x + v.y * v.y + v.z * v.z + v.w * v.w;
    }
    s += __shfl_down(s, 4, 8); sq += __shfl_down(sq, 4, 8);
    s += __shfl_down(s, 2, 8); sq += __shfl_down(sq, 2, 8);
    s += __shfl_down(s, 1, 8); sq += __shfl_down(sq, 1, 8);
    if (g == 0) {
      float mm = s * (1.f / 256.f);
      mst[r] = mm;
      rst[r] = 1.f / sqrtf(sq * (1.f / 256.f) - mm * mm + LNEPS);
    }
  }
  __syncthreads();
  for (int lidx = t; lidx < NSLOT * 256; lidx += 256) {
    const int i = lidx >> 8, kk = lidx & 255;
    U[i][kk] = (U[i][kk] - mst[i]) * rst[i];
  }
  __syncthreads();
  {
    const int d = t & 63, ig = t >> 6;
    const float* wrow = Wgq + (size_t)(h * 64 + d) * 256;
    float aq[6] = {};
    for (int k4 = 0; k4 < 256; k4 += 4) {
      const float4 wv = *(const float4*)(wrow + k4);
#pragma unroll
      for (int u = 0; u < 6; ++u) {
        const float4 uv = *(const float4*)&U[ig * 6 + u][k4];
        aq[u] += uv.x * wv.x + uv.y * wv.y + uv.z * wv.z + uv.w * wv.w;
      }
    }
    const float qc = cconst[512 + h * 64 + d];
#pragma unroll
    for (int u = 0; u < 6; ++u) qs[ig * 6 + u][d] = aq[u] + qc;
  }
  __syncthreads();
  const int j = jc * 256 + t;
  const float* kr = kmat + (size_t)(b * NFEAT + j) * 256 + h * 64;
  float acc[NSLOT] = {};
#pragma unroll
  for (int d4 = 0; d4 < DH; d4 += 4) {
    float4 kv = *(const float4*)(kr + d4);
#pragma unroll
    for (int i = 0; i < NSLOT; ++i) {
      float4 qv = *(const float4*)&qs[i][d4];
      acc[i] += qv.x * kv.x + qv.y * kv.y + qv.z * kv.z + qv.w * kv.w;
    }
  }
  float mx = -1e30f;
#pragma unroll
  for (int i = 0; i < NSLOT; ++i) { acc[i] *= QSCALE; mx = fmaxf(mx, acc[i]); }
  float s = 0.f;
#pragma unroll
  for (int i = 0; i < NSLOT; ++i) { acc[i] = expf(acc[i] - mx); s += acc[i]; }
  const float inv = 1.f / s;
  float* ab = attn + (size_t)(b * NH + h) * NSLOT * NFEAT + j;
#pragma unroll
  for (int i = 0; i < NSLOT; ++i) {
    const float wgt = acc[i] * inv;
    if (WRITE_ATTN) ab[(size_t)i * NFEAT] = wgt;
    U[i][t] = wgt + ATTN_EPS;
  }
  __syncthreads();
  if (t < 192) {
    const int i = t >> 3, s8 = t & 7;
    float sp = 0.f;
#pragma unroll
    for (int m = 0; m < 32; ++m) sp += U[i][s8 * 32 + ((m + t) & 31)];
    ssr[i][s8] = sp;
  }
  const int d = t & 63;
  const int ig = t >> 6;
  float acc2[6] = {};
  for (int j0 = 0; j0 < 256; j0 += 64) {
    __syncthreads();
#pragma unroll
    for (int rl = 0; rl < 4; ++rl) {
      const int lidx = rl * 1024 + t * 4;
      const int jj = lidx >> 6, dd = lidx & 63;
      *(float4*)&vt[jj][dd] =
          *(const float4*)(vmat + (size_t)(b * NFEAT + jc * 256 + j0 + jj) * 256 + h * 64 + dd);
    }
    __syncthreads();
#pragma unroll 16
    for (int jj = 0; jj < 64; ++jj) {
      const float vv = vt[jj][d];
#pragma unroll
      for (int u = 0; u < 6; ++u) acc2[u] += U[ig * 6 + u][j0 + jj] * vv;
    }
  }
  __syncthreads();
  if (t < NSLOT) {
    float sp = 0.f;
#pragma unroll
    for (int u = 0; u < 8; ++u) sp += ssr[t][u];
    ssump[((size_t)(b * NH + h) * 4 + jc) * NSLOT + t] = sp;
  }
  float* up = updp + (((size_t)(b * NH + h) * 4 + jc) * NSLOT) * 64;
#pragma unroll
  for (int u = 0; u < 6; ++u) up[(ig * 6 + u) * 64 + d] = acc2[u];
}

// ---- fused GRU with updfin fold; FINAL also writes out_slots ----
template <bool FINAL>
__global__ LB void k_grufin(const float* __restrict__ updp, const float* __restrict__ ssump,
                            const float* __restrict__ sprev,
                            const float* __restrict__ Wih, const float* __restrict__ Whh,
                            const float* __restrict__ bih, const float* __restrict__ bhh,
                            float* __restrict__ snext, float* __restrict__ outs) {
  __shared__ float updt[8][256];
  __shared__ float Bs[3][16][66];
  const int bx = blockIdx.x;
  const int d0 = blockIdx.y * 64;
  const int rows0 = bx * 8;
  const int t = threadIdx.x;
  {
    const int h = t >> 6, d = t & 63;
#pragma unroll
    for (int u = 0; u < 8; ++u) {
      const int row = rows0 + u;
      const int b = row / 24, i = row - b * 24;
      const size_t base = (size_t)(b * 4 + h) * 4;
      float s = 0.f, wsum = 0.f;
#pragma unroll
      for (int jc = 0; jc < 4; ++jc) {
        s += updp[(base + jc) * (NSLOT * 64) + i * 64 + d];
        wsum += ssump[(base + jc) * NSLOT + i];
      }
      updt[u][h * 64 + d] = s / wsum;
    }
  }
  __syncthreads();
  const int r = t >> 5;
  const int dd = (t & 31) * 2;
  const int bc = t >> 2;
  const int bk4 = (t & 3) * 4;
  float accR[2] = {}, accZ[2] = {}, accN[2] = {}, accH[2] = {};
  for (int k0 = 0; k0 < 256; k0 += 16) {
#pragma unroll
    for (int s = 0; s < 3; ++s) {
      float4 w = *(const float4*)(Wih + (size_t)(s * 256 + d0 + bc) * 256 + k0 + bk4);
      Bs[s][bk4 + 0][bc] = w.x; Bs[s][bk4 + 1][bc] = w.y;
      Bs[s][bk4 + 2][bc] = w.z; Bs[s][bk4 + 3][bc] = w.w;
    }
    __syncthreads();
#pragma unroll
    for (int kk = 0; kk < 16; ++kk) {
      const float a = updt[r][k0 + kk];
      const float2 b0 = *(const float2*)&Bs[0][kk][dd];
      const float2 b1 = *(const float2*)&Bs[1][kk][dd];
      const float2 b2 = *(const float2*)&Bs[2][kk][dd];
      accR[0] += a * b0.x; accR[1] += a * b0.y;
      accZ[0] += a * b1.x; accZ[1] += a * b1.y;
      accN[0] += a * b2.x; accN[1] += a * b2.y;
    }
    __syncthreads();
  }
  {
    const int rr2 = t >> 5, c0 = (t & 31) * 8;
    const float* sp = sprev + (size_t)(rows0 + rr2) * 256 + c0;
    *(float4*)&updt[rr2][c0] = *(const float4*)sp;
    *(float4*)&updt[rr2][c0 + 4] = *(const float4*)(sp + 4);
  }
  __syncthreads();
  for (int k0 = 0; k0 < 256; k0 += 16) {
#pragma unroll
    for (int s = 0; s < 3; ++s) {
      float4 w = *(const float4*)(Whh + (size_t)(s * 256 + d0 + bc) * 256 + k0 + bk4);
      Bs[s][bk4 + 0][bc] = w.x; Bs[s][bk4 + 1][bc] = w.y;
      Bs[s][bk4 + 2][bc] = w.z; Bs[s][bk4 + 3][bc] = w.w;
    }
    __syncthreads();
#pragma unroll
    for (int kk = 0; kk < 16; ++kk) {
      const float a = updt[r][k0 + kk];
      const float2 b0 = *(const float2*)&Bs[0][kk][dd];
      const float2 b1 = *(const float2*)&Bs[1][kk][dd];
      const float2 b2 = *(const float2*)&Bs[2][kk][dd];
      accR[0] += a * b0.x; accR[1] += a * b0.y;
      accZ[0] += a * b1.x; accZ[1] += a * b1.y;
      accH[0] += a * b2.x; accH[1] += a * b2.y;
    }
    __syncthreads();
  }
  const int row = rows0 + r;
  const float hpv[2] = {updt[r][d0 + dd], updt[r][d0 + dd + 1]};
  float o[2];
#pragma unroll
  for (int x = 0; x < 2; ++x) {
    const int c = d0 + dd + x;
    const float rr = 1.f / (1.f + expf(-(accR[x] + bih[c] + bhh[c])));
    const float zz = 1.f / (1.f + expf(-(accZ[x] + bih[256 + c] + bhh[256 + c])));
    const float nn = tanhf(accN[x] + bih[512 + c] + rr * (accH[x] + bhh[512 + c]));
    o[x] = (1.f - zz) * nn + zz * hpv[x];
  }
  *(float2*)(snext + (size_t)row * 256 + d0 + dd) = make_float2(o[0], o[1]);
  if (FINAL)
    *(float2*)(outs + (size_t)row * 256 + d0 + dd) = make_float2(o[0], o[1]);
}

// ---------------- attn_vis = mean over heads ----------------
__global__ LB void k_attnvis(const float* __restrict__ attn, float* __restrict__ out) {
  const int idx = blockIdx.x * 256 + threadIdx.x;
  const int j = idx & 1023;
  const int rem = idx >> 10;
  const int i = rem % NSLOT;
  const int b = rem / NSLOT;
  float s = 0.f;
#pragma unroll
  for (int h = 0; h < NH; ++h)
    s += attn[(size_t)((b * NH + h) * NSLOT + i) * NFEAT + j];
  out[idx] = 0.25f * s;
}

// ---- VQ argmin (ref formula) + straight-through in-place (round-4 proven) ----
__global__ LB void k_vq(float* __restrict__ slots, const float* __restrict__ cb,
                        float* __restrict__ idx_out, float* __restrict__ bestd2) {
  const int r = blockIdx.x;
  const int t = threadIdx.x;
  __shared__ float xs[256];
  __shared__ float red[256];
  __shared__ float rv[256];
  __shared__ int ri[256];
  xs[t] = slots[(size_t)r * 256 + t];
  __syncthreads();
  red[t] = xs[t] * xs[t]; __syncthreads();
  for (int o = 128; o > 0; o >>= 1) { if (t < o) red[t] += red[t + o]; __syncthreads(); }
  const float x2 = red[0];
  float best = 1e30f; int bidx = 0;
#pragma unroll
  for (int cset = 0; cset < 2; ++cset) {
    const int c = cset * 256 + t;
    const float* cr = cb + (size_t)c * 256;
    float xc = 0.f, cc = 0.f;
    for (int dd = 0; dd < 256; dd += 4) {
      float4 cv = *(const float4*)(cr + dd);
      xc += xs[dd] * cv.x + xs[dd + 1] * cv.y + xs[dd + 2] * cv.z + xs[dd + 3] * cv.w;
      cc += cv.x * cv.x + cv.y * cv.y + cv.z * cv.z + cv.w * cv.w;
    }
    float d2 = x2 - 2.f * xc + cc;
    if (d2 < best) { best = d2; bidx = c; }
  }
  rv[t] = best; ri[t] = bidx; __syncthreads();
  for (int o = 128; o > 0; o >>= 1) {
    if (t < o) {
      if (rv[t + o] < rv[t] || (rv[t + o] == rv[t] && ri[t + o] < ri[t])) {
        rv[t] = rv[t + o]; ri[t] = ri[t + o];
      }
    }
    __syncthreads();
  }
  const int wi = ri[0];
  const float cval = cb[(size_t)wi * 256 + t];
  const float diff = xs[t] - cval;
  red[t] = diff * diff; __syncthreads();
  for (int o = 128; o > 0; o >>= 1) { if (t < o) red[t] += red[t + o]; __syncthreads(); }
  if (t == 0) { idx_out[r] = (float)wi; bestd2[r] = red[0]; }
  slots[(size_t)r * 256 + t] = cval;
}

__global__ LB void k_commit(const float* __restrict__ bestd2, float* __restrict__ out) {
  const int t = threadIdx.x;
  __shared__ float red[256];
  float s = 0.f;
  for (int i = t; i < MS; i += 256) s += bestd2[i];
  red[t] = s; __syncthreads();
  for (int o = 128; o > 0; o >>= 1) { if (t < o) red[t] += red[t + o]; __syncthreads(); }
  if (t == 0) out[0] = red[0] / (float)(MS * 256);
}

extern "C" void kernel_launch(void* const* d_in, const int* in_sizes, int n_in,
                              void* d_out, int out_size, void* d_ws, size_t ws_size,
                              hipStream_t stream) {
  const float* features = (const float*)d_in[0];
  const float* cond = (const float*)d_in[1];
  const float* Wq = (const float*)d_in[2];
  const float* Wk = (const float*)d_in[3];
  const float* Wv = (const float*)d_in[4];
  const float* g_in = (const float*)d_in[5];
  const float* b_in = (const float*)d_in[6];
  const float* g_s = (const float*)d_in[7];
  const float* b_s = (const float*)d_in[8];
  const float* Wih = (const float*)d_in[9];
  const float* Whh = (const float*)d_in[10];
  const float* bih = (const float*)d_in[11];
  const float* bhh = (const float*)d_in[12];
  const float* cb = (const float*)d_in[13];
  float* out = (float*)d_out;

  char* wsb = (char*)d_ws;
  short* Bh_g = (short*)wsb; wsb += (size_t)512 * FDIM * 2;
  short* Bl_g = (short*)wsb; wsb += (size_t)512 * FDIM * 2;
  float* ws = (float*)wsb;
  float* stats = ws;  ws += 2 * MF;
  float* kbuf = ws;   ws += (size_t)MF * 256;
  float* vbuf = ws;   ws += (size_t)MF * 256;
  float* attn = ws;   ws += (size_t)BATCH * NH * NSLOT * NFEAT;
  float* sbufA = ws;  ws += (size_t)MS * 256;
  float* sbufB = ws;  ws += (size_t)MS * 256;
  float* updp = ws;   ws += (size_t)512 * NSLOT * 64;
  float* ssump = ws;  ws += (size_t)512 * NSLOT;
  float* Wgq = ws;    ws += 256 * 256;
  float* cconst = ws; ws += 768;
  float* bestd2 = ws; ws += MS;

  float* out_slots = out;
  float* out_post = out + 196608;
  float* out_pre = out + 196608 + 786432;
  float* out_idx = out + 196608 + 786432 * 2;
  float* out_commit = out_idx + 768;

  k_preprow<<<MF / 4 + 768, 256, 0, stream>>>(features, stats, Wk, Wv, Wq, g_in, b_in,
                                              g_s, b_s, Bh_g, Bl_g, Wgq, cconst);
  k_mfkv<<<dim3(MF / 128, 4), 256, 0, stream>>>(features, stats, Bh_g, Bl_g, cconst, kbuf, vbuf);

  const float* scur = cond;  // iteration 0 reads conditioning directly
  float* bufs[2] = {sbufA, sbufB};
  int nb = 0;
  for (int call = 0; call < 2; ++call) {
    for (int it = 0; it < NITER; ++it) {
      float* snxt = bufs[nb]; nb ^= 1;
      if (it == NITER - 1)
        k_fdots<true><<<512, 256, 0, stream>>>(scur, Wgq, cconst, kbuf, vbuf, attn, updp, ssump);
      else
        k_fdots<false><<<512, 256, 0, stream>>>(scur, Wgq, cconst, kbuf, vbuf, attn, updp, ssump);
      if (call == 1 && it == NITER - 1)
        k_grufin<true><<<dim3(MS / 8, 4), 256, 0, stream>>>(updp, ssump, scur, Wih, Whh,
                                                            bih, bhh, snxt, out_slots);
      else
        k_grufin<false><<<dim3(MS / 8, 4), 256, 0, stream>>>(updp, ssump, scur, Wih, Whh,
                                                             bih, bhh, snxt, out_slots);
      scur = snxt;
    }
    k_attnvis<<<BATCH * NSLOT * NFEAT / 256, 256, 0, stream>>>(attn, call ? out_post : out_pre);
    if (call == 0) {
      k_vq<<<MS, 256, 0, stream>>>((float*)scur, cb, out_idx, bestd2);
      k_commit<<<1, 256, 0, stream>>>(bestd2, out_commit);
    }
  }
}